// Round 2
// baseline (1601.465 us; speedup 1.0000x reference)
//
#include <hip/hip_runtime.h>

// 3-layer GCN (fp32 end-to-end): CSR-by-dst build + (GEMM -> gather-aggregate) x3
// + final linear. All float tensors are fp32 (threshold ~2^-16 relative rules out
// bf16 anywhere); edge_index arrives as int32 per harness contract.

#define N_NODES 200000
#define N_EDGES 3200000

static_assert(N_NODES % 64 == 0, "gemm tiling");
static_assert(N_EDGES % 256 == 0, "edge grid");

// ---------------- degree / CSR build ----------------

__global__ __launch_bounds__(256) void k_count(const int* __restrict__ dst,
                                               int* __restrict__ deg) {
    int e = blockIdx.x * 256 + threadIdx.x;
    atomicAdd(&deg[dst[e]], 1);
}

__global__ __launch_bounds__(256) void k_dinv(const int* __restrict__ deg,
                                              float* __restrict__ dinv) {
    int i = blockIdx.x * 256 + threadIdx.x;
    if (i < N_NODES) dinv[i] = rsqrtf((float)(deg[i] + 1));  // +1 self-loop
}

// exclusive scan of deg -> row_ptr (block-local), bsum = per-block totals
__global__ __launch_bounds__(256) void k_scan1(const int* __restrict__ deg,
                                               int* __restrict__ row,
                                               int* __restrict__ bsum) {
    __shared__ int sm[256];
    int t = threadIdx.x;
    int base = blockIdx.x * 1024 + t * 4;
    int a0 = (base + 0 < N_NODES) ? deg[base + 0] : 0;
    int a1 = (base + 1 < N_NODES) ? deg[base + 1] : 0;
    int a2 = (base + 2 < N_NODES) ? deg[base + 2] : 0;
    int a3 = (base + 3 < N_NODES) ? deg[base + 3] : 0;
    int s = a0 + a1 + a2 + a3;
    sm[t] = s;
    __syncthreads();
    for (int o = 1; o < 256; o <<= 1) {
        int v = (t >= o) ? sm[t - o] : 0;
        __syncthreads();
        sm[t] += v;
        __syncthreads();
    }
    int excl = sm[t] - s;
    if (base + 0 < N_NODES) row[base + 0] = excl;
    if (base + 1 < N_NODES) row[base + 1] = excl + a0;
    if (base + 2 < N_NODES) row[base + 2] = excl + a0 + a1;
    if (base + 3 < N_NODES) row[base + 3] = excl + a0 + a1 + a2;
    if (t == 255) bsum[blockIdx.x] = sm[255];
}

__global__ __launch_bounds__(256) void k_scan2(int* __restrict__ bsum) {
    constexpr int NB = (N_NODES + 1023) / 1024;  // 196
    __shared__ int sm[256];
    int t = threadIdx.x;
    int v = (t < NB) ? bsum[t] : 0;
    sm[t] = v;
    __syncthreads();
    for (int o = 1; o < 256; o <<= 1) {
        int u = (t >= o) ? sm[t - o] : 0;
        __syncthreads();
        sm[t] += u;
        __syncthreads();
    }
    if (t < NB) bsum[t] = sm[t] - v;  // exclusive
}

__global__ __launch_bounds__(256) void k_scan3(int* __restrict__ row,
                                               const int* __restrict__ bsum,
                                               int* __restrict__ cursor) {
    int i = blockIdx.x * 256 + threadIdx.x;
    if (i < N_NODES) {
        int v = row[i] + bsum[i >> 10];
        row[i] = v;
        cursor[i] = v;
    }
    if (i == 0) row[N_NODES] = N_EDGES;
}

__global__ __launch_bounds__(256) void k_fill(const int* __restrict__ src,
                                              const int* __restrict__ dst,
                                              int* __restrict__ cursor,
                                              int* __restrict__ col) {
    int e = blockIdx.x * 256 + threadIdx.x;
    int d = dst[e];
    int p = atomicAdd(&cursor[d], 1);
    col[p] = src[e];
}

// ---------------- GEMM layer 1: [N,258]x[258,128] fp32 -----------------------
// K=256 tiled; rows 256 (history) and 257 (is_subgoal) folded in as a tail.

__global__ __launch_bounds__(256) void k_gemm1(const float* __restrict__ X,
                                               const float* __restrict__ hist,
                                               const float* __restrict__ subg,
                                               const float* __restrict__ W,
                                               float* __restrict__ out) {
    __shared__ float Xs[64][33];    // [node][k], +1 pad
    __shared__ float Ws[32][132];   // [k][f], +4 pad (keeps float4 alignment)
    const int t = threadIdx.x;
    const int nb = blockIdx.x * 64;
    const int fi = t & 15;          // feature group: f = fi*8 .. fi*8+7
    const int ni = t >> 4;          // node group: n = ni*4 .. ni*4+3
    const int lxn = t >> 2;         // X loader: node 0..63
    const int lxk = (t & 3) * 8;    //            k-offset 0/8/16/24
    const int lwk = t >> 3;         // W loader: k row 0..31
    const int lwf = (t & 7) * 16;   //            f-offset, 16 elems

    float acc[4][8];
#pragma unroll
    for (int n = 0; n < 4; ++n)
#pragma unroll
        for (int f = 0; f < 8; ++f) acc[n][f] = 0.f;

    for (int kc = 0; kc < 256; kc += 32) {
        const float* xp = X + (size_t)(nb + lxn) * 256 + kc + lxk;
        float4 xa = *(const float4*)xp;
        float4 xb = *(const float4*)(xp + 4);
        Xs[lxn][lxk + 0] = xa.x;
        Xs[lxn][lxk + 1] = xa.y;
        Xs[lxn][lxk + 2] = xa.z;
        Xs[lxn][lxk + 3] = xa.w;
        Xs[lxn][lxk + 4] = xb.x;
        Xs[lxn][lxk + 5] = xb.y;
        Xs[lxn][lxk + 6] = xb.z;
        Xs[lxn][lxk + 7] = xb.w;

        const float* wp = W + (size_t)(kc + lwk) * 128 + lwf;
        float4* wsp = (float4*)&Ws[lwk][lwf];
        wsp[0] = *(const float4*)(wp + 0);
        wsp[1] = *(const float4*)(wp + 4);
        wsp[2] = *(const float4*)(wp + 8);
        wsp[3] = *(const float4*)(wp + 12);
        __syncthreads();

#pragma unroll
        for (int kk = 0; kk < 32; ++kk) {
            float4 wa = *(const float4*)&Ws[kk][fi * 8];
            float4 wb = *(const float4*)&Ws[kk][fi * 8 + 4];
#pragma unroll
            for (int n = 0; n < 4; ++n) {
                float xv = Xs[ni * 4 + n][kk];
                acc[n][0] += xv * wa.x;
                acc[n][1] += xv * wa.y;
                acc[n][2] += xv * wa.z;
                acc[n][3] += xv * wa.w;
                acc[n][4] += xv * wb.x;
                acc[n][5] += xv * wb.y;
                acc[n][6] += xv * wb.z;
                acc[n][7] += xv * wb.w;
            }
        }
        __syncthreads();
    }

    // K tail: rows 256 (history) and 257 (is_subgoal)
    float hh[4], ss[4];
#pragma unroll
    for (int n = 0; n < 4; ++n) {
        hh[n] = hist[nb + ni * 4 + n];
        ss[n] = subg[nb + ni * 4 + n];
    }
#pragma unroll
    for (int f = 0; f < 8; ++f) {
        float w256 = W[256 * 128 + fi * 8 + f];
        float w257 = W[257 * 128 + fi * 8 + f];
#pragma unroll
        for (int n = 0; n < 4; ++n) acc[n][f] += hh[n] * w256 + ss[n] * w257;
    }

#pragma unroll
    for (int n = 0; n < 4; ++n) {
        float* op = out + (size_t)(nb + ni * 4 + n) * 128 + fi * 8;
        *(float4*)op = make_float4(acc[n][0], acc[n][1], acc[n][2], acc[n][3]);
        *(float4*)(op + 4) = make_float4(acc[n][4], acc[n][5], acc[n][6], acc[n][7]);
    }
}

// ---------------- GEMM layer 2: [N,128]x[128,64] fp32 ------------------------

__global__ __launch_bounds__(256) void k_gemm2(const float* __restrict__ Xin,
                                               const float* __restrict__ W,
                                               float* __restrict__ out) {
    __shared__ float Xs[64][33];
    __shared__ float Ws[32][68];
    const int t = threadIdx.x;
    const int nb = blockIdx.x * 64;
    const int fi = t & 15;          // f = fi*4 .. +3
    const int ni = t >> 4;          // n = ni*4 .. +3
    const int lxn = t >> 2;
    const int lxk = (t & 3) * 8;
    const int lwk = t >> 3;
    const int lwf = (t & 7) * 8;

    float acc[4][4];
#pragma unroll
    for (int n = 0; n < 4; ++n)
#pragma unroll
        for (int f = 0; f < 4; ++f) acc[n][f] = 0.f;

    for (int kc = 0; kc < 128; kc += 32) {
        const float* xp = Xin + (size_t)(nb + lxn) * 128 + kc + lxk;
        float4 xa = *(const float4*)xp;
        float4 xb = *(const float4*)(xp + 4);
        Xs[lxn][lxk + 0] = xa.x;
        Xs[lxn][lxk + 1] = xa.y;
        Xs[lxn][lxk + 2] = xa.z;
        Xs[lxn][lxk + 3] = xa.w;
        Xs[lxn][lxk + 4] = xb.x;
        Xs[lxn][lxk + 5] = xb.y;
        Xs[lxn][lxk + 6] = xb.z;
        Xs[lxn][lxk + 7] = xb.w;

        const float* wp = W + (size_t)(kc + lwk) * 64 + lwf;
        float4* wsp = (float4*)&Ws[lwk][lwf];
        wsp[0] = *(const float4*)(wp + 0);
        wsp[1] = *(const float4*)(wp + 4);
        __syncthreads();

#pragma unroll
        for (int kk = 0; kk < 32; ++kk) {
            float4 wv = *(const float4*)&Ws[kk][fi * 4];
#pragma unroll
            for (int n = 0; n < 4; ++n) {
                float xv = Xs[ni * 4 + n][kk];
                acc[n][0] += xv * wv.x;
                acc[n][1] += xv * wv.y;
                acc[n][2] += xv * wv.z;
                acc[n][3] += xv * wv.w;
            }
        }
        __syncthreads();
    }

#pragma unroll
    for (int n = 0; n < 4; ++n) {
        float* op = out + (size_t)(nb + ni * 4 + n) * 64 + fi * 4;
        *(float4*)op = make_float4(acc[n][0], acc[n][1], acc[n][2], acc[n][3]);
    }
}

// ---------------- GEMM layer 3: [N,64]x[64,8] --------------------------------

__global__ __launch_bounds__(256) void k_gemm3(const float* __restrict__ Xin,
                                               const float* __restrict__ W,
                                               float* __restrict__ out) {
    __shared__ float Ws[512];  // 64x8
    int t = threadIdx.x;
    Ws[t] = W[t];
    Ws[t + 256] = W[t + 256];
    __syncthreads();
    int i = blockIdx.x * 256 + t;
    if (i >= N_NODES) return;
    const float4* xp = (const float4*)(Xin + (size_t)i * 64);
    float acc[8];
#pragma unroll
    for (int f = 0; f < 8; ++f) acc[f] = 0.f;
#pragma unroll
    for (int k4 = 0; k4 < 16; ++k4) {
        float4 xv = xp[k4];
        float xs[4] = {xv.x, xv.y, xv.z, xv.w};
#pragma unroll
        for (int q = 0; q < 4; ++q) {
            int k = k4 * 4 + q;
            float4 w0 = *(const float4*)&Ws[k * 8];
            float4 w1 = *(const float4*)&Ws[k * 8 + 4];
            acc[0] += xs[q] * w0.x;
            acc[1] += xs[q] * w0.y;
            acc[2] += xs[q] * w0.z;
            acc[3] += xs[q] * w0.w;
            acc[4] += xs[q] * w1.x;
            acc[5] += xs[q] * w1.y;
            acc[6] += xs[q] * w1.z;
            acc[7] += xs[q] * w1.w;
        }
    }
    float* op = out + (size_t)i * 8;
    *(float4*)op = make_float4(acc[0], acc[1], acc[2], acc[3]);
    *(float4*)(op + 4) = make_float4(acc[4], acc[5], acc[6], acc[7]);
}

// ------- aggregation: out[i] = relu(dinv_i*(sum_j dinv_j*h_j + dinv_i*h_i) + b)

template <int F, int TPN>
__global__ __launch_bounds__(256) void k_agg(const float* __restrict__ hlin,
                                             const int* __restrict__ row,
                                             const int* __restrict__ col,
                                             const float* __restrict__ dinv,
                                             const float* __restrict__ bias,
                                             float* __restrict__ out) {
    constexpr int FPT = F / TPN;
    constexpr int NPB = 256 / TPN;
    const int t = threadIdx.x;
    const int node = blockIdx.x * NPB + t / TPN;
    const int lane = t % TPN;
    const int fbase = lane * FPT;

    float acc[FPT];
#pragma unroll
    for (int q = 0; q < FPT; ++q) acc[q] = 0.f;

    const int s = row[node];
    const int e = row[node + 1];
    for (int idx = s; idx < e; ++idx) {
        const int j = col[idx];
        const float w = dinv[j];
        const float* hp = hlin + (size_t)j * F + fbase;
#pragma unroll
        for (int q = 0; q < FPT; ++q) acc[q] += w * hp[q];
    }
    const float di = dinv[node];
    const float* hs = hlin + (size_t)node * F + fbase;
    float* op = out + (size_t)node * F + fbase;
#pragma unroll
    for (int q = 0; q < FPT; ++q) {
        float v = di * (acc[q] + di * hs[q]) + bias[fbase + q];
        op[q] = fmaxf(v, 0.f);
    }
}

// ---------------- final linear: [N,8]x[8,3] + bc -----------------------------

__global__ __launch_bounds__(256) void k_final(const float* __restrict__ h,
                                               const float* __restrict__ Wc,
                                               const float* __restrict__ bc,
                                               float* __restrict__ out) {
    int i = blockIdx.x * 256 + threadIdx.x;
    if (i >= N_NODES) return;
    const float4* xp = (const float4*)(h + (size_t)i * 8);
    float4 x0 = xp[0], x1 = xp[1];
    float xs[8] = {x0.x, x0.y, x0.z, x0.w, x1.x, x1.y, x1.z, x1.w};
    float o0 = bc[0], o1 = bc[1], o2 = bc[2];
#pragma unroll
    for (int k = 0; k < 8; ++k) {
        o0 += xs[k] * Wc[k * 3 + 0];
        o1 += xs[k] * Wc[k * 3 + 1];
        o2 += xs[k] * Wc[k * 3 + 2];
    }
    out[(size_t)i * 3 + 0] = o0;
    out[(size_t)i * 3 + 1] = o1;
    out[(size_t)i * 3 + 2] = o2;
}

// ---------------- launch -----------------------------------------------------

extern "C" void kernel_launch(void* const* d_in, const int* in_sizes, int n_in,
                              void* d_out, int out_size, void* d_ws, size_t ws_size,
                              hipStream_t stream) {
    const float* latent = (const float*)d_in[0];
    const float* hist = (const float*)d_in[1];
    const float* subg = (const float*)d_in[2];
    const int* eidx = (const int*)d_in[3];
    const float* W1 = (const float*)d_in[4];
    const float* b1 = (const float*)d_in[5];
    const float* W2 = (const float*)d_in[6];
    const float* b2 = (const float*)d_in[7];
    const float* W3 = (const float*)d_in[8];
    const float* b3 = (const float*)d_in[9];
    const float* Wc = (const float*)d_in[10];
    const float* bc = (const float*)d_in[11];
    float* outp = (float*)d_out;

    char* ws = (char*)d_ws;
    size_t off = 0;
    auto take = [&](size_t bytes) -> void* {
        void* p = ws + off;
        off += (bytes + 255) & ~(size_t)255;
        return p;
    };
    float* dinv = (float*)take((size_t)N_NODES * 4);
    int* deg = (int*)take((size_t)N_NODES * 4);
    int* row = (int*)take((size_t)(N_NODES + 1) * 4);
    int* cursor = (int*)take((size_t)N_NODES * 4);
    int* col = (int*)take((size_t)N_EDGES * 4);
    int* bsum = (int*)take(256 * 4);
    float* bufA = (float*)take((size_t)N_NODES * 128 * 4);
    float* bufB = (float*)take((size_t)N_NODES * 128 * 4);

    const int* srcp = eidx;            // edge_index[0]
    const int* dstp = eidx + N_EDGES;  // edge_index[1]

    hipMemsetAsync(deg, 0, (size_t)N_NODES * 4, stream);
    k_count<<<N_EDGES / 256, 256, 0, stream>>>(dstp, deg);
    k_dinv<<<(N_NODES + 255) / 256, 256, 0, stream>>>(deg, dinv);
    k_scan1<<<(N_NODES + 1023) / 1024, 256, 0, stream>>>(deg, row, bsum);
    k_scan2<<<1, 256, 0, stream>>>(bsum);
    k_scan3<<<(N_NODES + 255) / 256, 256, 0, stream>>>(row, bsum, cursor);
    k_fill<<<N_EDGES / 256, 256, 0, stream>>>(srcp, dstp, cursor, col);

    k_gemm1<<<N_NODES / 64, 256, 0, stream>>>(latent, hist, subg, W1, bufA);
    k_agg<128, 64><<<N_NODES / 4, 256, 0, stream>>>(bufA, row, col, dinv, b1, bufB);
    k_gemm2<<<N_NODES / 64, 256, 0, stream>>>(bufB, W2, bufA);
    k_agg<64, 64><<<N_NODES / 4, 256, 0, stream>>>(bufA, row, col, dinv, b2, bufB);
    k_gemm3<<<(N_NODES + 255) / 256, 256, 0, stream>>>(bufB, W3, bufA);
    k_agg<8, 8><<<N_NODES / 32, 256, 0, stream>>>(bufA, row, col, dinv, b3, bufB);
    k_final<<<(N_NODES + 255) / 256, 256, 0, stream>>>(bufB, Wc, bc, outp);
}

// Round 3
// 1325.916 us; speedup vs baseline: 1.2078x; 1.2078x over previous
//
#include <hip/hip_runtime.h>

// 3-layer GCN (fp32 end-to-end): CSR-by-dst build + (GEMM -> gather-aggregate) x3
// + final linear. Round 3: k_agg edge loop unrolled x4 with batched independent
// loads (latency-bound gather -> 8 memory ops in flight per wave), k_agg<64>
// switched to TPN=32 (8B lane loads, 2 node streams/wave).

#define N_NODES 200000
#define N_EDGES 3200000

static_assert(N_NODES % 64 == 0, "gemm tiling");
static_assert(N_EDGES % 256 == 0, "edge grid");

// ---------------- degree / CSR build ----------------

__global__ __launch_bounds__(256) void k_count(const int* __restrict__ dst,
                                               int* __restrict__ deg) {
    int e = blockIdx.x * 256 + threadIdx.x;
    atomicAdd(&deg[dst[e]], 1);
}

__global__ __launch_bounds__(256) void k_dinv(const int* __restrict__ deg,
                                              float* __restrict__ dinv) {
    int i = blockIdx.x * 256 + threadIdx.x;
    if (i < N_NODES) dinv[i] = rsqrtf((float)(deg[i] + 1));  // +1 self-loop
}

// exclusive scan of deg -> row_ptr (block-local), bsum = per-block totals
__global__ __launch_bounds__(256) void k_scan1(const int* __restrict__ deg,
                                               int* __restrict__ row,
                                               int* __restrict__ bsum) {
    __shared__ int sm[256];
    int t = threadIdx.x;
    int base = blockIdx.x * 1024 + t * 4;
    int a0 = (base + 0 < N_NODES) ? deg[base + 0] : 0;
    int a1 = (base + 1 < N_NODES) ? deg[base + 1] : 0;
    int a2 = (base + 2 < N_NODES) ? deg[base + 2] : 0;
    int a3 = (base + 3 < N_NODES) ? deg[base + 3] : 0;
    int s = a0 + a1 + a2 + a3;
    sm[t] = s;
    __syncthreads();
    for (int o = 1; o < 256; o <<= 1) {
        int v = (t >= o) ? sm[t - o] : 0;
        __syncthreads();
        sm[t] += v;
        __syncthreads();
    }
    int excl = sm[t] - s;
    if (base + 0 < N_NODES) row[base + 0] = excl;
    if (base + 1 < N_NODES) row[base + 1] = excl + a0;
    if (base + 2 < N_NODES) row[base + 2] = excl + a0 + a1;
    if (base + 3 < N_NODES) row[base + 3] = excl + a0 + a1 + a2;
    if (t == 255) bsum[blockIdx.x] = sm[255];
}

__global__ __launch_bounds__(256) void k_scan2(int* __restrict__ bsum) {
    constexpr int NB = (N_NODES + 1023) / 1024;  // 196
    __shared__ int sm[256];
    int t = threadIdx.x;
    int v = (t < NB) ? bsum[t] : 0;
    sm[t] = v;
    __syncthreads();
    for (int o = 1; o < 256; o <<= 1) {
        int u = (t >= o) ? sm[t - o] : 0;
        __syncthreads();
        sm[t] += u;
        __syncthreads();
    }
    if (t < NB) bsum[t] = sm[t] - v;  // exclusive
}

__global__ __launch_bounds__(256) void k_scan3(int* __restrict__ row,
                                               const int* __restrict__ bsum,
                                               int* __restrict__ cursor) {
    int i = blockIdx.x * 256 + threadIdx.x;
    if (i < N_NODES) {
        int v = row[i] + bsum[i >> 10];
        row[i] = v;
        cursor[i] = v;
    }
    if (i == 0) row[N_NODES] = N_EDGES;
}

__global__ __launch_bounds__(256) void k_fill(const int* __restrict__ src,
                                              const int* __restrict__ dst,
                                              int* __restrict__ cursor,
                                              int* __restrict__ col) {
    int e = blockIdx.x * 256 + threadIdx.x;
    int d = dst[e];
    int p = atomicAdd(&cursor[d], 1);
    col[p] = src[e];
}

// ---------------- GEMM layer 1: [N,258]x[258,128] fp32 -----------------------
// K=256 tiled; rows 256 (history) and 257 (is_subgoal) folded in as a tail.

__global__ __launch_bounds__(256) void k_gemm1(const float* __restrict__ X,
                                               const float* __restrict__ hist,
                                               const float* __restrict__ subg,
                                               const float* __restrict__ W,
                                               float* __restrict__ out) {
    __shared__ float Xs[64][33];    // [node][k], +1 pad
    __shared__ float Ws[32][132];   // [k][f], +4 pad (keeps float4 alignment)
    const int t = threadIdx.x;
    const int nb = blockIdx.x * 64;
    const int fi = t & 15;          // feature group: f = fi*8 .. fi*8+7
    const int ni = t >> 4;          // node group: n = ni*4 .. ni*4+3
    const int lxn = t >> 2;         // X loader: node 0..63
    const int lxk = (t & 3) * 8;    //            k-offset 0/8/16/24
    const int lwk = t >> 3;         // W loader: k row 0..31
    const int lwf = (t & 7) * 16;   //            f-offset, 16 elems

    float acc[4][8];
#pragma unroll
    for (int n = 0; n < 4; ++n)
#pragma unroll
        for (int f = 0; f < 8; ++f) acc[n][f] = 0.f;

    for (int kc = 0; kc < 256; kc += 32) {
        const float* xp = X + (size_t)(nb + lxn) * 256 + kc + lxk;
        float4 xa = *(const float4*)xp;
        float4 xb = *(const float4*)(xp + 4);
        Xs[lxn][lxk + 0] = xa.x;
        Xs[lxn][lxk + 1] = xa.y;
        Xs[lxn][lxk + 2] = xa.z;
        Xs[lxn][lxk + 3] = xa.w;
        Xs[lxn][lxk + 4] = xb.x;
        Xs[lxn][lxk + 5] = xb.y;
        Xs[lxn][lxk + 6] = xb.z;
        Xs[lxn][lxk + 7] = xb.w;

        const float* wp = W + (size_t)(kc + lwk) * 128 + lwf;
        float4* wsp = (float4*)&Ws[lwk][lwf];
        wsp[0] = *(const float4*)(wp + 0);
        wsp[1] = *(const float4*)(wp + 4);
        wsp[2] = *(const float4*)(wp + 8);
        wsp[3] = *(const float4*)(wp + 12);
        __syncthreads();

#pragma unroll
        for (int kk = 0; kk < 32; ++kk) {
            float4 wa = *(const float4*)&Ws[kk][fi * 8];
            float4 wb = *(const float4*)&Ws[kk][fi * 8 + 4];
#pragma unroll
            for (int n = 0; n < 4; ++n) {
                float xv = Xs[ni * 4 + n][kk];
                acc[n][0] += xv * wa.x;
                acc[n][1] += xv * wa.y;
                acc[n][2] += xv * wa.z;
                acc[n][3] += xv * wa.w;
                acc[n][4] += xv * wb.x;
                acc[n][5] += xv * wb.y;
                acc[n][6] += xv * wb.z;
                acc[n][7] += xv * wb.w;
            }
        }
        __syncthreads();
    }

    // K tail: rows 256 (history) and 257 (is_subgoal)
    float hh[4], ss[4];
#pragma unroll
    for (int n = 0; n < 4; ++n) {
        hh[n] = hist[nb + ni * 4 + n];
        ss[n] = subg[nb + ni * 4 + n];
    }
#pragma unroll
    for (int f = 0; f < 8; ++f) {
        float w256 = W[256 * 128 + fi * 8 + f];
        float w257 = W[257 * 128 + fi * 8 + f];
#pragma unroll
        for (int n = 0; n < 4; ++n) acc[n][f] += hh[n] * w256 + ss[n] * w257;
    }

#pragma unroll
    for (int n = 0; n < 4; ++n) {
        float* op = out + (size_t)(nb + ni * 4 + n) * 128 + fi * 8;
        *(float4*)op = make_float4(acc[n][0], acc[n][1], acc[n][2], acc[n][3]);
        *(float4*)(op + 4) = make_float4(acc[n][4], acc[n][5], acc[n][6], acc[n][7]);
    }
}

// ---------------- GEMM layer 2: [N,128]x[128,64] fp32 ------------------------

__global__ __launch_bounds__(256) void k_gemm2(const float* __restrict__ Xin,
                                               const float* __restrict__ W,
                                               float* __restrict__ out) {
    __shared__ float Xs[64][33];
    __shared__ float Ws[32][68];
    const int t = threadIdx.x;
    const int nb = blockIdx.x * 64;
    const int fi = t & 15;          // f = fi*4 .. +3
    const int ni = t >> 4;          // n = ni*4 .. +3
    const int lxn = t >> 2;
    const int lxk = (t & 3) * 8;
    const int lwk = t >> 3;
    const int lwf = (t & 7) * 8;

    float acc[4][4];
#pragma unroll
    for (int n = 0; n < 4; ++n)
#pragma unroll
        for (int f = 0; f < 4; ++f) acc[n][f] = 0.f;

    for (int kc = 0; kc < 128; kc += 32) {
        const float* xp = Xin + (size_t)(nb + lxn) * 128 + kc + lxk;
        float4 xa = *(const float4*)xp;
        float4 xb = *(const float4*)(xp + 4);
        Xs[lxn][lxk + 0] = xa.x;
        Xs[lxn][lxk + 1] = xa.y;
        Xs[lxn][lxk + 2] = xa.z;
        Xs[lxn][lxk + 3] = xa.w;
        Xs[lxn][lxk + 4] = xb.x;
        Xs[lxn][lxk + 5] = xb.y;
        Xs[lxn][lxk + 6] = xb.z;
        Xs[lxn][lxk + 7] = xb.w;

        const float* wp = W + (size_t)(kc + lwk) * 64 + lwf;
        float4* wsp = (float4*)&Ws[lwk][lwf];
        wsp[0] = *(const float4*)(wp + 0);
        wsp[1] = *(const float4*)(wp + 4);
        __syncthreads();

#pragma unroll
        for (int kk = 0; kk < 32; ++kk) {
            float4 wv = *(const float4*)&Ws[kk][fi * 4];
#pragma unroll
            for (int n = 0; n < 4; ++n) {
                float xv = Xs[ni * 4 + n][kk];
                acc[n][0] += xv * wv.x;
                acc[n][1] += xv * wv.y;
                acc[n][2] += xv * wv.z;
                acc[n][3] += xv * wv.w;
            }
        }
        __syncthreads();
    }

#pragma unroll
    for (int n = 0; n < 4; ++n) {
        float* op = out + (size_t)(nb + ni * 4 + n) * 64 + fi * 4;
        *(float4*)op = make_float4(acc[n][0], acc[n][1], acc[n][2], acc[n][3]);
    }
}

// ---------------- GEMM layer 3: [N,64]x[64,8] --------------------------------

__global__ __launch_bounds__(256) void k_gemm3(const float* __restrict__ Xin,
                                               const float* __restrict__ W,
                                               float* __restrict__ out) {
    __shared__ float Ws[512];  // 64x8
    int t = threadIdx.x;
    Ws[t] = W[t];
    Ws[t + 256] = W[t + 256];
    __syncthreads();
    int i = blockIdx.x * 256 + t;
    if (i >= N_NODES) return;
    const float4* xp = (const float4*)(Xin + (size_t)i * 64);
    float acc[8];
#pragma unroll
    for (int f = 0; f < 8; ++f) acc[f] = 0.f;
#pragma unroll
    for (int k4 = 0; k4 < 16; ++k4) {
        float4 xv = xp[k4];
        float xs[4] = {xv.x, xv.y, xv.z, xv.w};
#pragma unroll
        for (int q = 0; q < 4; ++q) {
            int k = k4 * 4 + q;
            float4 w0 = *(const float4*)&Ws[k * 8];
            float4 w1 = *(const float4*)&Ws[k * 8 + 4];
            acc[0] += xs[q] * w0.x;
            acc[1] += xs[q] * w0.y;
            acc[2] += xs[q] * w0.z;
            acc[3] += xs[q] * w0.w;
            acc[4] += xs[q] * w1.x;
            acc[5] += xs[q] * w1.y;
            acc[6] += xs[q] * w1.z;
            acc[7] += xs[q] * w1.w;
        }
    }
    float* op = out + (size_t)i * 8;
    *(float4*)op = make_float4(acc[0], acc[1], acc[2], acc[3]);
    *(float4*)(op + 4) = make_float4(acc[4], acc[5], acc[6], acc[7]);
}

// ------- aggregation: out[i] = relu(dinv_i*(sum_j dinv_j*h_j + dinv_i*h_i) + b)
// Edge loop unrolled x4: batch 4 col loads, 4 dinv loads, 4 row loads before
// accumulating -> ~8 independent memory ops in flight per wave (latency-bound).

template <int F, int TPN>
__global__ __launch_bounds__(256) void k_agg(const float* __restrict__ hlin,
                                             const int* __restrict__ row,
                                             const int* __restrict__ col,
                                             const float* __restrict__ dinv,
                                             const float* __restrict__ bias,
                                             float* __restrict__ out) {
    constexpr int FPT = F / TPN;
    constexpr int NPB = 256 / TPN;
    const int t = threadIdx.x;
    const int node = blockIdx.x * NPB + t / TPN;
    const int lane = t % TPN;
    const int fbase = lane * FPT;

    float acc[FPT];
#pragma unroll
    for (int q = 0; q < FPT; ++q) acc[q] = 0.f;

    const int s = row[node];
    const int e = row[node + 1];
    int idx = s;
    for (; idx + 4 <= e; idx += 4) {
        const int j0 = col[idx + 0];
        const int j1 = col[idx + 1];
        const int j2 = col[idx + 2];
        const int j3 = col[idx + 3];
        const float w0 = dinv[j0];
        const float w1 = dinv[j1];
        const float w2 = dinv[j2];
        const float w3 = dinv[j3];
        const float* p0 = hlin + (size_t)j0 * F + fbase;
        const float* p1 = hlin + (size_t)j1 * F + fbase;
        const float* p2 = hlin + (size_t)j2 * F + fbase;
        const float* p3 = hlin + (size_t)j3 * F + fbase;
        float h0[FPT], h1[FPT], h2[FPT], h3[FPT];
#pragma unroll
        for (int q = 0; q < FPT; ++q) h0[q] = p0[q];
#pragma unroll
        for (int q = 0; q < FPT; ++q) h1[q] = p1[q];
#pragma unroll
        for (int q = 0; q < FPT; ++q) h2[q] = p2[q];
#pragma unroll
        for (int q = 0; q < FPT; ++q) h3[q] = p3[q];
#pragma unroll
        for (int q = 0; q < FPT; ++q)
            acc[q] += w0 * h0[q] + w1 * h1[q] + w2 * h2[q] + w3 * h3[q];
    }
    for (; idx < e; ++idx) {
        const int j = col[idx];
        const float w = dinv[j];
        const float* hp = hlin + (size_t)j * F + fbase;
#pragma unroll
        for (int q = 0; q < FPT; ++q) acc[q] += w * hp[q];
    }
    const float di = dinv[node];
    const float* hs = hlin + (size_t)node * F + fbase;
    float* op = out + (size_t)node * F + fbase;
#pragma unroll
    for (int q = 0; q < FPT; ++q) {
        float v = di * (acc[q] + di * hs[q]) + bias[fbase + q];
        op[q] = fmaxf(v, 0.f);
    }
}

// ---------------- final linear: [N,8]x[8,3] + bc -----------------------------

__global__ __launch_bounds__(256) void k_final(const float* __restrict__ h,
                                               const float* __restrict__ Wc,
                                               const float* __restrict__ bc,
                                               float* __restrict__ out) {
    int i = blockIdx.x * 256 + threadIdx.x;
    if (i >= N_NODES) return;
    const float4* xp = (const float4*)(h + (size_t)i * 8);
    float4 x0 = xp[0], x1 = xp[1];
    float xs[8] = {x0.x, x0.y, x0.z, x0.w, x1.x, x1.y, x1.z, x1.w};
    float o0 = bc[0], o1 = bc[1], o2 = bc[2];
#pragma unroll
    for (int k = 0; k < 8; ++k) {
        o0 += xs[k] * Wc[k * 3 + 0];
        o1 += xs[k] * Wc[k * 3 + 1];
        o2 += xs[k] * Wc[k * 3 + 2];
    }
    out[(size_t)i * 3 + 0] = o0;
    out[(size_t)i * 3 + 1] = o1;
    out[(size_t)i * 3 + 2] = o2;
}

// ---------------- launch -----------------------------------------------------

extern "C" void kernel_launch(void* const* d_in, const int* in_sizes, int n_in,
                              void* d_out, int out_size, void* d_ws, size_t ws_size,
                              hipStream_t stream) {
    const float* latent = (const float*)d_in[0];
    const float* hist = (const float*)d_in[1];
    const float* subg = (const float*)d_in[2];
    const int* eidx = (const int*)d_in[3];
    const float* W1 = (const float*)d_in[4];
    const float* b1 = (const float*)d_in[5];
    const float* W2 = (const float*)d_in[6];
    const float* b2 = (const float*)d_in[7];
    const float* W3 = (const float*)d_in[8];
    const float* b3 = (const float*)d_in[9];
    const float* Wc = (const float*)d_in[10];
    const float* bc = (const float*)d_in[11];
    float* outp = (float*)d_out;

    char* ws = (char*)d_ws;
    size_t off = 0;
    auto take = [&](size_t bytes) -> void* {
        void* p = ws + off;
        off += (bytes + 255) & ~(size_t)255;
        return p;
    };
    float* dinv = (float*)take((size_t)N_NODES * 4);
    int* deg = (int*)take((size_t)N_NODES * 4);
    int* row = (int*)take((size_t)(N_NODES + 1) * 4);
    int* cursor = (int*)take((size_t)N_NODES * 4);
    int* col = (int*)take((size_t)N_EDGES * 4);
    int* bsum = (int*)take(256 * 4);
    float* bufA = (float*)take((size_t)N_NODES * 128 * 4);
    float* bufB = (float*)take((size_t)N_NODES * 128 * 4);

    const int* srcp = eidx;            // edge_index[0]
    const int* dstp = eidx + N_EDGES;  // edge_index[1]

    hipMemsetAsync(deg, 0, (size_t)N_NODES * 4, stream);
    k_count<<<N_EDGES / 256, 256, 0, stream>>>(dstp, deg);
    k_dinv<<<(N_NODES + 255) / 256, 256, 0, stream>>>(deg, dinv);
    k_scan1<<<(N_NODES + 1023) / 1024, 256, 0, stream>>>(deg, row, bsum);
    k_scan2<<<1, 256, 0, stream>>>(bsum);
    k_scan3<<<(N_NODES + 255) / 256, 256, 0, stream>>>(row, bsum, cursor);
    k_fill<<<N_EDGES / 256, 256, 0, stream>>>(srcp, dstp, cursor, col);

    k_gemm1<<<N_NODES / 64, 256, 0, stream>>>(latent, hist, subg, W1, bufA);
    k_agg<128, 64><<<N_NODES / 4, 256, 0, stream>>>(bufA, row, col, dinv, b1, bufB);
    k_gemm2<<<N_NODES / 64, 256, 0, stream>>>(bufB, W2, bufA);
    k_agg<64, 32><<<N_NODES / 8, 256, 0, stream>>>(bufA, row, col, dinv, b2, bufB);
    k_gemm3<<<(N_NODES + 255) / 256, 256, 0, stream>>>(bufB, W3, bufA);
    k_agg<8, 8><<<N_NODES / 32, 256, 0, stream>>>(bufA, row, col, dinv, b3, bufB);
    k_final<<<(N_NODES + 255) / 256, 256, 0, stream>>>(bufB, Wc, bc, outp);
}

// Round 4
// 1045.347 us; speedup vs baseline: 1.5320x; 1.2684x over previous
//
#include <hip/hip_runtime.h>

// 3-layer GCN (fp32): bucketed CSR build (write-amplification fix) +
// (GEMM -> gather-aggregate) x3 + final linear.
// Round 4: k_fill's 203MB partial-line scatter (64B line per 4B write, cross-XCD
// bounce) replaced by bucket pipeline: bhist -> bscan -> chunked scatter of
// packed u32 entries -> per-bucket prep (deg/row/dinv/col in one L2-local pass).
// k_agg edge loop unroll 4 -> 8.

#define N_NODES 200000
#define N_EDGES 3200000
#define NBUCK 782            // ceil(200000/256)

static_assert(N_NODES % 64 == 0, "gemm tiling");
static_assert((NBUCK - 1) * 256 < N_NODES && NBUCK * 256 >= N_NODES, "buckets");

typedef unsigned int u32;

// ---------------- bucket histogram ----------------

__global__ __launch_bounds__(256) void k_bhist(const int* __restrict__ dst,
                                               int* __restrict__ bcnt) {
    __shared__ int lh[NBUCK];
    int t = threadIdx.x;
    for (int b = t; b < NBUCK; b += 256) lh[b] = 0;
    __syncthreads();
    long e0 = (long)blockIdx.x * 8192;
    for (int k = 0; k < 32; ++k) {
        long e = e0 + k * 256 + t;
        if (e < N_EDGES) atomicAdd(&lh[dst[e] >> 8], 1);
    }
    __syncthreads();
    for (int b = t; b < NBUCK; b += 256)
        if (lh[b]) atomicAdd(&bcnt[b], lh[b]);
}

// ---------------- bucket scan (1 block) ----------------

__global__ __launch_bounds__(256) void k_bscan(const int* __restrict__ bcnt,
                                               int* __restrict__ boff,
                                               int* __restrict__ bcur,
                                               int* __restrict__ row) {
    __shared__ int sm[256];
    int t = threadIdx.x;
    int base = t * 4;
    int a0 = (base + 0 < NBUCK) ? bcnt[base + 0] : 0;
    int a1 = (base + 1 < NBUCK) ? bcnt[base + 1] : 0;
    int a2 = (base + 2 < NBUCK) ? bcnt[base + 2] : 0;
    int a3 = (base + 3 < NBUCK) ? bcnt[base + 3] : 0;
    int s = a0 + a1 + a2 + a3;
    sm[t] = s;
    __syncthreads();
    for (int o = 1; o < 256; o <<= 1) {
        int v = (t >= o) ? sm[t - o] : 0;
        __syncthreads();
        sm[t] += v;
        __syncthreads();
    }
    int excl = sm[t] - s;
    if (base + 0 < NBUCK) { boff[base + 0] = excl;            bcur[base + 0] = excl; }
    if (base + 1 < NBUCK) { boff[base + 1] = excl + a0;        bcur[base + 1] = excl + a0; }
    if (base + 2 < NBUCK) { boff[base + 2] = excl + a0 + a1;   bcur[base + 2] = excl + a0 + a1; }
    if (base + 3 < NBUCK) { boff[base + 3] = excl + a0 + a1 + a2; bcur[base + 3] = excl + a0 + a1 + a2; }
    if (t == 255) { boff[NBUCK] = N_EDGES; row[N_NODES] = N_EDGES; }
}

// ------------- chunked scatter: entries[p] = (src<<8)|dst_local -------------

__global__ __launch_bounds__(256) void k_scatter(const int* __restrict__ src,
                                                 const int* __restrict__ dst,
                                                 int* __restrict__ bcur,
                                                 u32* __restrict__ entries) {
    __shared__ int lh[NBUCK];
    __shared__ int base[NBUCK];
    __shared__ int lcur[NBUCK];
    int t = threadIdx.x;
    for (int b = t; b < NBUCK; b += 256) lh[b] = 0;
    __syncthreads();
    long e0 = (long)blockIdx.x * 8192;
    for (int k = 0; k < 32; ++k) {
        long e = e0 + k * 256 + t;
        if (e < N_EDGES) atomicAdd(&lh[dst[e] >> 8], 1);
    }
    __syncthreads();
    for (int b = t; b < NBUCK; b += 256) {
        base[b] = atomicAdd(&bcur[b], lh[b]);
        lcur[b] = 0;
    }
    __syncthreads();
    for (int k = 0; k < 32; ++k) {
        long e = e0 + k * 256 + t;
        if (e < N_EDGES) {
            int d = dst[e];
            int bkt = d >> 8;
            int p = base[bkt] + atomicAdd(&lcur[bkt], 1);
            entries[p] = ((u32)src[e] << 8) | (u32)(d & 255);
        }
    }
}

// --- per-bucket prep: deg/row/dinv + col fill, all L2-local to one block ----

__global__ __launch_bounds__(256) void k_prep(const u32* __restrict__ entries,
                                              const int* __restrict__ boff,
                                              int* __restrict__ row,
                                              float* __restrict__ dinv,
                                              int* __restrict__ col) {
    __shared__ int lh[256];
    __shared__ int sc[256];
    __shared__ int cur[256];
    const int b = blockIdx.x, t = threadIdx.x;
    const int s = boff[b], e = boff[b + 1];
    const int cnt = e - s;
    lh[t] = 0;
    __syncthreads();
    for (int i = t; i < cnt; i += 256) atomicAdd(&lh[entries[s + i] & 255], 1);
    __syncthreads();
    int my = lh[t];
    sc[t] = my;
    __syncthreads();
    for (int o = 1; o < 256; o <<= 1) {
        int v = (t >= o) ? sc[t - o] : 0;
        __syncthreads();
        sc[t] += v;
        __syncthreads();
    }
    int excl = sc[t] - my;
    int node = b * 256 + t;
    if (node < N_NODES) {
        row[node] = s + excl;
        dinv[node] = rsqrtf((float)(my + 1));  // +1 self-loop
    }
    cur[t] = s + excl;
    __syncthreads();
    for (int i = t; i < cnt; i += 256) {
        u32 en = entries[s + i];
        int p = atomicAdd(&cur[en & 255], 1);
        col[p] = (int)(en >> 8);
    }
}

// ---------------- GEMM layer 1: [N,258]x[258,128] fp32 -----------------------

__global__ __launch_bounds__(256) void k_gemm1(const float* __restrict__ X,
                                               const float* __restrict__ hist,
                                               const float* __restrict__ subg,
                                               const float* __restrict__ W,
                                               float* __restrict__ out) {
    __shared__ float Xs[64][33];
    __shared__ float Ws[32][132];
    const int t = threadIdx.x;
    const int nb = blockIdx.x * 64;
    const int fi = t & 15;
    const int ni = t >> 4;
    const int lxn = t >> 2;
    const int lxk = (t & 3) * 8;
    const int lwk = t >> 3;
    const int lwf = (t & 7) * 16;

    float acc[4][8];
#pragma unroll
    for (int n = 0; n < 4; ++n)
#pragma unroll
        for (int f = 0; f < 8; ++f) acc[n][f] = 0.f;

    for (int kc = 0; kc < 256; kc += 32) {
        const float* xp = X + (size_t)(nb + lxn) * 256 + kc + lxk;
        float4 xa = *(const float4*)xp;
        float4 xb = *(const float4*)(xp + 4);
        Xs[lxn][lxk + 0] = xa.x;
        Xs[lxn][lxk + 1] = xa.y;
        Xs[lxn][lxk + 2] = xa.z;
        Xs[lxn][lxk + 3] = xa.w;
        Xs[lxn][lxk + 4] = xb.x;
        Xs[lxn][lxk + 5] = xb.y;
        Xs[lxn][lxk + 6] = xb.z;
        Xs[lxn][lxk + 7] = xb.w;

        const float* wp = W + (size_t)(kc + lwk) * 128 + lwf;
        float4* wsp = (float4*)&Ws[lwk][lwf];
        wsp[0] = *(const float4*)(wp + 0);
        wsp[1] = *(const float4*)(wp + 4);
        wsp[2] = *(const float4*)(wp + 8);
        wsp[3] = *(const float4*)(wp + 12);
        __syncthreads();

#pragma unroll
        for (int kk = 0; kk < 32; ++kk) {
            float4 wa = *(const float4*)&Ws[kk][fi * 8];
            float4 wb = *(const float4*)&Ws[kk][fi * 8 + 4];
#pragma unroll
            for (int n = 0; n < 4; ++n) {
                float xv = Xs[ni * 4 + n][kk];
                acc[n][0] += xv * wa.x;
                acc[n][1] += xv * wa.y;
                acc[n][2] += xv * wa.z;
                acc[n][3] += xv * wa.w;
                acc[n][4] += xv * wb.x;
                acc[n][5] += xv * wb.y;
                acc[n][6] += xv * wb.z;
                acc[n][7] += xv * wb.w;
            }
        }
        __syncthreads();
    }

    float hh[4], ss[4];
#pragma unroll
    for (int n = 0; n < 4; ++n) {
        hh[n] = hist[nb + ni * 4 + n];
        ss[n] = subg[nb + ni * 4 + n];
    }
#pragma unroll
    for (int f = 0; f < 8; ++f) {
        float w256 = W[256 * 128 + fi * 8 + f];
        float w257 = W[257 * 128 + fi * 8 + f];
#pragma unroll
        for (int n = 0; n < 4; ++n) acc[n][f] += hh[n] * w256 + ss[n] * w257;
    }

#pragma unroll
    for (int n = 0; n < 4; ++n) {
        float* op = out + (size_t)(nb + ni * 4 + n) * 128 + fi * 8;
        *(float4*)op = make_float4(acc[n][0], acc[n][1], acc[n][2], acc[n][3]);
        *(float4*)(op + 4) = make_float4(acc[n][4], acc[n][5], acc[n][6], acc[n][7]);
    }
}

// ---------------- GEMM layer 2: [N,128]x[128,64] fp32 ------------------------

__global__ __launch_bounds__(256) void k_gemm2(const float* __restrict__ Xin,
                                               const float* __restrict__ W,
                                               float* __restrict__ out) {
    __shared__ float Xs[64][33];
    __shared__ float Ws[32][68];
    const int t = threadIdx.x;
    const int nb = blockIdx.x * 64;
    const int fi = t & 15;
    const int ni = t >> 4;
    const int lxn = t >> 2;
    const int lxk = (t & 3) * 8;
    const int lwk = t >> 3;
    const int lwf = (t & 7) * 8;

    float acc[4][4];
#pragma unroll
    for (int n = 0; n < 4; ++n)
#pragma unroll
        for (int f = 0; f < 4; ++f) acc[n][f] = 0.f;

    for (int kc = 0; kc < 128; kc += 32) {
        const float* xp = Xin + (size_t)(nb + lxn) * 128 + kc + lxk;
        float4 xa = *(const float4*)xp;
        float4 xb = *(const float4*)(xp + 4);
        Xs[lxn][lxk + 0] = xa.x;
        Xs[lxn][lxk + 1] = xa.y;
        Xs[lxn][lxk + 2] = xa.z;
        Xs[lxn][lxk + 3] = xa.w;
        Xs[lxn][lxk + 4] = xb.x;
        Xs[lxn][lxk + 5] = xb.y;
        Xs[lxn][lxk + 6] = xb.z;
        Xs[lxn][lxk + 7] = xb.w;

        const float* wp = W + (size_t)(kc + lwk) * 64 + lwf;
        float4* wsp = (float4*)&Ws[lwk][lwf];
        wsp[0] = *(const float4*)(wp + 0);
        wsp[1] = *(const float4*)(wp + 4);
        __syncthreads();

#pragma unroll
        for (int kk = 0; kk < 32; ++kk) {
            float4 wv = *(const float4*)&Ws[kk][fi * 4];
#pragma unroll
            for (int n = 0; n < 4; ++n) {
                float xv = Xs[ni * 4 + n][kk];
                acc[n][0] += xv * wv.x;
                acc[n][1] += xv * wv.y;
                acc[n][2] += xv * wv.z;
                acc[n][3] += xv * wv.w;
            }
        }
        __syncthreads();
    }

#pragma unroll
    for (int n = 0; n < 4; ++n) {
        float* op = out + (size_t)(nb + ni * 4 + n) * 64 + fi * 4;
        *(float4*)op = make_float4(acc[n][0], acc[n][1], acc[n][2], acc[n][3]);
    }
}

// ---------------- GEMM layer 3: [N,64]x[64,8] --------------------------------

__global__ __launch_bounds__(256) void k_gemm3(const float* __restrict__ Xin,
                                               const float* __restrict__ W,
                                               float* __restrict__ out) {
    __shared__ float Ws[512];
    int t = threadIdx.x;
    Ws[t] = W[t];
    Ws[t + 256] = W[t + 256];
    __syncthreads();
    int i = blockIdx.x * 256 + t;
    if (i >= N_NODES) return;
    const float4* xp = (const float4*)(Xin + (size_t)i * 64);
    float acc[8];
#pragma unroll
    for (int f = 0; f < 8; ++f) acc[f] = 0.f;
#pragma unroll
    for (int k4 = 0; k4 < 16; ++k4) {
        float4 xv = xp[k4];
        float xs[4] = {xv.x, xv.y, xv.z, xv.w};
#pragma unroll
        for (int q = 0; q < 4; ++q) {
            int k = k4 * 4 + q;
            float4 w0 = *(const float4*)&Ws[k * 8];
            float4 w1 = *(const float4*)&Ws[k * 8 + 4];
            acc[0] += xs[q] * w0.x;
            acc[1] += xs[q] * w0.y;
            acc[2] += xs[q] * w0.z;
            acc[3] += xs[q] * w0.w;
            acc[4] += xs[q] * w1.x;
            acc[5] += xs[q] * w1.y;
            acc[6] += xs[q] * w1.z;
            acc[7] += xs[q] * w1.w;
        }
    }
    float* op = out + (size_t)i * 8;
    *(float4*)op = make_float4(acc[0], acc[1], acc[2], acc[3]);
    *(float4*)(op + 4) = make_float4(acc[4], acc[5], acc[6], acc[7]);
}

// ------- aggregation: out[i] = relu(dinv_i*(sum_j dinv_j*h_j + dinv_i*h_i) + b)
// Edge loop unrolled x8 (batched independent loads for MLP).

template <int F, int TPN>
__global__ __launch_bounds__(256) void k_agg(const float* __restrict__ hlin,
                                             const int* __restrict__ row,
                                             const int* __restrict__ col,
                                             const float* __restrict__ dinv,
                                             const float* __restrict__ bias,
                                             float* __restrict__ out) {
    constexpr int FPT = F / TPN;
    constexpr int NPB = 256 / TPN;
    const int t = threadIdx.x;
    const int node = blockIdx.x * NPB + t / TPN;
    const int lane = t % TPN;
    const int fbase = lane * FPT;

    float acc[FPT];
#pragma unroll
    for (int q = 0; q < FPT; ++q) acc[q] = 0.f;

    const int s = row[node];
    const int e = row[node + 1];
    int idx = s;
    for (; idx + 8 <= e; idx += 8) {
        int j[8];
        float w[8];
        const float* p[8];
#pragma unroll
        for (int u = 0; u < 8; ++u) j[u] = col[idx + u];
#pragma unroll
        for (int u = 0; u < 8; ++u) w[u] = dinv[j[u]];
#pragma unroll
        for (int u = 0; u < 8; ++u) p[u] = hlin + (size_t)j[u] * F + fbase;
        float h[8][FPT];
#pragma unroll
        for (int u = 0; u < 8; ++u)
#pragma unroll
            for (int q = 0; q < FPT; ++q) h[u][q] = p[u][q];
#pragma unroll
        for (int q = 0; q < FPT; ++q) {
            float a = 0.f;
#pragma unroll
            for (int u = 0; u < 8; ++u) a += w[u] * h[u][q];
            acc[q] += a;
        }
    }
    for (; idx < e; ++idx) {
        const int j = col[idx];
        const float w = dinv[j];
        const float* hp = hlin + (size_t)j * F + fbase;
#pragma unroll
        for (int q = 0; q < FPT; ++q) acc[q] += w * hp[q];
    }
    const float di = dinv[node];
    const float* hs = hlin + (size_t)node * F + fbase;
    float* op = out + (size_t)node * F + fbase;
#pragma unroll
    for (int q = 0; q < FPT; ++q) {
        float v = di * (acc[q] + di * hs[q]) + bias[fbase + q];
        op[q] = fmaxf(v, 0.f);
    }
}

// ---------------- final linear: [N,8]x[8,3] + bc -----------------------------

__global__ __launch_bounds__(256) void k_final(const float* __restrict__ h,
                                               const float* __restrict__ Wc,
                                               const float* __restrict__ bc,
                                               float* __restrict__ out) {
    int i = blockIdx.x * 256 + threadIdx.x;
    if (i >= N_NODES) return;
    const float4* xp = (const float4*)(h + (size_t)i * 8);
    float4 x0 = xp[0], x1 = xp[1];
    float xs[8] = {x0.x, x0.y, x0.z, x0.w, x1.x, x1.y, x1.z, x1.w};
    float o0 = bc[0], o1 = bc[1], o2 = bc[2];
#pragma unroll
    for (int k = 0; k < 8; ++k) {
        o0 += xs[k] * Wc[k * 3 + 0];
        o1 += xs[k] * Wc[k * 3 + 1];
        o2 += xs[k] * Wc[k * 3 + 2];
    }
    out[(size_t)i * 3 + 0] = o0;
    out[(size_t)i * 3 + 1] = o1;
    out[(size_t)i * 3 + 2] = o2;
}

// ---------------- launch -----------------------------------------------------

extern "C" void kernel_launch(void* const* d_in, const int* in_sizes, int n_in,
                              void* d_out, int out_size, void* d_ws, size_t ws_size,
                              hipStream_t stream) {
    const float* latent = (const float*)d_in[0];
    const float* hist = (const float*)d_in[1];
    const float* subg = (const float*)d_in[2];
    const int* eidx = (const int*)d_in[3];
    const float* W1 = (const float*)d_in[4];
    const float* b1 = (const float*)d_in[5];
    const float* W2 = (const float*)d_in[6];
    const float* b2 = (const float*)d_in[7];
    const float* W3 = (const float*)d_in[8];
    const float* b3 = (const float*)d_in[9];
    const float* Wc = (const float*)d_in[10];
    const float* bc = (const float*)d_in[11];
    float* outp = (float*)d_out;

    char* ws = (char*)d_ws;
    size_t off = 0;
    auto take = [&](size_t bytes) -> void* {
        void* p = ws + off;
        off += (bytes + 255) & ~(size_t)255;
        return p;
    };
    float* dinv = (float*)take((size_t)N_NODES * 4);
    int* row = (int*)take((size_t)(N_NODES + 1) * 4);
    int* col = (int*)take((size_t)N_EDGES * 4);
    u32* entries = (u32*)take((size_t)N_EDGES * 4);
    int* bcnt = (int*)take((size_t)NBUCK * 4);
    int* boff = (int*)take((size_t)(NBUCK + 1) * 4);
    int* bcur = (int*)take((size_t)NBUCK * 4);
    float* bufA = (float*)take((size_t)N_NODES * 128 * 4);
    float* bufB = (float*)take((size_t)N_NODES * 128 * 4);

    const int* srcp = eidx;            // edge_index[0]
    const int* dstp = eidx + N_EDGES;  // edge_index[1]

    const int scat_blocks = (N_EDGES + 8191) / 8192;  // 391

    hipMemsetAsync(bcnt, 0, (size_t)NBUCK * 4, stream);
    k_bhist<<<scat_blocks, 256, 0, stream>>>(dstp, bcnt);
    k_bscan<<<1, 256, 0, stream>>>(bcnt, boff, bcur, row);
    k_scatter<<<scat_blocks, 256, 0, stream>>>(srcp, dstp, bcur, entries);
    k_prep<<<NBUCK, 256, 0, stream>>>(entries, boff, row, dinv, col);

    k_gemm1<<<N_NODES / 64, 256, 0, stream>>>(latent, hist, subg, W1, bufA);
    k_agg<128, 64><<<N_NODES / 4, 256, 0, stream>>>(bufA, row, col, dinv, b1, bufB);
    k_gemm2<<<N_NODES / 64, 256, 0, stream>>>(bufB, W2, bufA);
    k_agg<64, 32><<<N_NODES / 8, 256, 0, stream>>>(bufA, row, col, dinv, b2, bufB);
    k_gemm3<<<(N_NODES + 255) / 256, 256, 0, stream>>>(bufB, W3, bufA);
    k_agg<8, 8><<<N_NODES / 32, 256, 0, stream>>>(bufA, row, col, dinv, b3, bufB);
    k_final<<<(N_NODES + 255) / 256, 256, 0, stream>>>(bufB, Wc, bc, outp);
}

// Round 5
// 905.067 us; speedup vs baseline: 1.7694x; 1.1550x over previous
//
#include <hip/hip_runtime.h>
#include <hip/hip_fp16.h>

// 3-layer GCN (fp32 compute): bucketed CSR build + (GEMM -> gather-aggregate) x3
// + final linear.
// Round 5: gather payload compression. GEMM epilogues write g = dinv*h (dinv
// folded in -> no per-edge dinv load, shorter dep chain) in fp16 for layers 1-2
// (halves the ~1.6GB random-gather traffic that was at its cache-hierarchy
// service ceiling). Layer 3 (F=8) stays fp32 with dinv-fold.

#define N_NODES 200000
#define N_EDGES 3200000
#define NBUCK 782            // ceil(200000/256)

static_assert(N_NODES % 64 == 0, "gemm tiling");
static_assert((NBUCK - 1) * 256 < N_NODES && NBUCK * 256 >= N_NODES, "buckets");

typedef unsigned int u32;

// ---------------- bucket histogram ----------------

__global__ __launch_bounds__(256) void k_bhist(const int* __restrict__ dst,
                                               int* __restrict__ bcnt) {
    __shared__ int lh[NBUCK];
    int t = threadIdx.x;
    for (int b = t; b < NBUCK; b += 256) lh[b] = 0;
    __syncthreads();
    long e0 = (long)blockIdx.x * 8192;
    for (int k = 0; k < 32; ++k) {
        long e = e0 + k * 256 + t;
        if (e < N_EDGES) atomicAdd(&lh[dst[e] >> 8], 1);
    }
    __syncthreads();
    for (int b = t; b < NBUCK; b += 256)
        if (lh[b]) atomicAdd(&bcnt[b], lh[b]);
}

// ---------------- bucket scan (1 block) ----------------

__global__ __launch_bounds__(256) void k_bscan(const int* __restrict__ bcnt,
                                               int* __restrict__ boff,
                                               int* __restrict__ bcur,
                                               int* __restrict__ row) {
    __shared__ int sm[256];
    int t = threadIdx.x;
    int base = t * 4;
    int a0 = (base + 0 < NBUCK) ? bcnt[base + 0] : 0;
    int a1 = (base + 1 < NBUCK) ? bcnt[base + 1] : 0;
    int a2 = (base + 2 < NBUCK) ? bcnt[base + 2] : 0;
    int a3 = (base + 3 < NBUCK) ? bcnt[base + 3] : 0;
    int s = a0 + a1 + a2 + a3;
    sm[t] = s;
    __syncthreads();
    for (int o = 1; o < 256; o <<= 1) {
        int v = (t >= o) ? sm[t - o] : 0;
        __syncthreads();
        sm[t] += v;
        __syncthreads();
    }
    int excl = sm[t] - s;
    if (base + 0 < NBUCK) { boff[base + 0] = excl;               bcur[base + 0] = excl; }
    if (base + 1 < NBUCK) { boff[base + 1] = excl + a0;          bcur[base + 1] = excl + a0; }
    if (base + 2 < NBUCK) { boff[base + 2] = excl + a0 + a1;     bcur[base + 2] = excl + a0 + a1; }
    if (base + 3 < NBUCK) { boff[base + 3] = excl + a0 + a1 + a2; bcur[base + 3] = excl + a0 + a1 + a2; }
    if (t == 255) { boff[NBUCK] = N_EDGES; row[N_NODES] = N_EDGES; }
}

// ------------- chunked scatter: entries[p] = (src<<8)|dst_local -------------

__global__ __launch_bounds__(256) void k_scatter(const int* __restrict__ src,
                                                 const int* __restrict__ dst,
                                                 int* __restrict__ bcur,
                                                 u32* __restrict__ entries) {
    __shared__ int lh[NBUCK];
    __shared__ int base[NBUCK];
    __shared__ int lcur[NBUCK];
    int t = threadIdx.x;
    for (int b = t; b < NBUCK; b += 256) lh[b] = 0;
    __syncthreads();
    long e0 = (long)blockIdx.x * 8192;
    for (int k = 0; k < 32; ++k) {
        long e = e0 + k * 256 + t;
        if (e < N_EDGES) atomicAdd(&lh[dst[e] >> 8], 1);
    }
    __syncthreads();
    for (int b = t; b < NBUCK; b += 256) {
        base[b] = atomicAdd(&bcur[b], lh[b]);
        lcur[b] = 0;
    }
    __syncthreads();
    for (int k = 0; k < 32; ++k) {
        long e = e0 + k * 256 + t;
        if (e < N_EDGES) {
            int d = dst[e];
            int bkt = d >> 8;
            int p = base[bkt] + atomicAdd(&lcur[bkt], 1);
            entries[p] = ((u32)src[e] << 8) | (u32)(d & 255);
        }
    }
}

// --- per-bucket prep: deg/row/dinv + col fill, all L2-local to one block ----

__global__ __launch_bounds__(256) void k_prep(const u32* __restrict__ entries,
                                              const int* __restrict__ boff,
                                              int* __restrict__ row,
                                              float* __restrict__ dinv,
                                              int* __restrict__ col) {
    __shared__ int lh[256];
    __shared__ int sc[256];
    __shared__ int cur[256];
    const int b = blockIdx.x, t = threadIdx.x;
    const int s = boff[b], e = boff[b + 1];
    const int cnt = e - s;
    lh[t] = 0;
    __syncthreads();
    for (int i = t; i < cnt; i += 256) atomicAdd(&lh[entries[s + i] & 255], 1);
    __syncthreads();
    int my = lh[t];
    sc[t] = my;
    __syncthreads();
    for (int o = 1; o < 256; o <<= 1) {
        int v = (t >= o) ? sc[t - o] : 0;
        __syncthreads();
        sc[t] += v;
        __syncthreads();
    }
    int excl = sc[t] - my;
    int node = b * 256 + t;
    if (node < N_NODES) {
        row[node] = s + excl;
        dinv[node] = rsqrtf((float)(my + 1));  // +1 self-loop
    }
    cur[t] = s + excl;
    __syncthreads();
    for (int i = t; i < cnt; i += 256) {
        u32 en = entries[s + i];
        int p = atomicAdd(&cur[en & 255], 1);
        col[p] = (int)(en >> 8);
    }
}

// ------- GEMM layer 1: [N,258]x[258,128] fp32, epilogue g = dinv*h -> fp16 ---

__global__ __launch_bounds__(256) void k_gemm1(const float* __restrict__ X,
                                               const float* __restrict__ hist,
                                               const float* __restrict__ subg,
                                               const float* __restrict__ W,
                                               const float* __restrict__ dinv,
                                               __half2* __restrict__ g1) {
    __shared__ float Xs[64][33];
    __shared__ float Ws[32][132];
    const int t = threadIdx.x;
    const int nb = blockIdx.x * 64;
    const int fi = t & 15;
    const int ni = t >> 4;
    const int lxn = t >> 2;
    const int lxk = (t & 3) * 8;
    const int lwk = t >> 3;
    const int lwf = (t & 7) * 16;

    float acc[4][8];
#pragma unroll
    for (int n = 0; n < 4; ++n)
#pragma unroll
        for (int f = 0; f < 8; ++f) acc[n][f] = 0.f;

    for (int kc = 0; kc < 256; kc += 32) {
        const float* xp = X + (size_t)(nb + lxn) * 256 + kc + lxk;
        float4 xa = *(const float4*)xp;
        float4 xb = *(const float4*)(xp + 4);
        Xs[lxn][lxk + 0] = xa.x;
        Xs[lxn][lxk + 1] = xa.y;
        Xs[lxn][lxk + 2] = xa.z;
        Xs[lxn][lxk + 3] = xa.w;
        Xs[lxn][lxk + 4] = xb.x;
        Xs[lxn][lxk + 5] = xb.y;
        Xs[lxn][lxk + 6] = xb.z;
        Xs[lxn][lxk + 7] = xb.w;

        const float* wp = W + (size_t)(kc + lwk) * 128 + lwf;
        float4* wsp = (float4*)&Ws[lwk][lwf];
        wsp[0] = *(const float4*)(wp + 0);
        wsp[1] = *(const float4*)(wp + 4);
        wsp[2] = *(const float4*)(wp + 8);
        wsp[3] = *(const float4*)(wp + 12);
        __syncthreads();

#pragma unroll
        for (int kk = 0; kk < 32; ++kk) {
            float4 wa = *(const float4*)&Ws[kk][fi * 8];
            float4 wb = *(const float4*)&Ws[kk][fi * 8 + 4];
#pragma unroll
            for (int n = 0; n < 4; ++n) {
                float xv = Xs[ni * 4 + n][kk];
                acc[n][0] += xv * wa.x;
                acc[n][1] += xv * wa.y;
                acc[n][2] += xv * wa.z;
                acc[n][3] += xv * wa.w;
                acc[n][4] += xv * wb.x;
                acc[n][5] += xv * wb.y;
                acc[n][6] += xv * wb.z;
                acc[n][7] += xv * wb.w;
            }
        }
        __syncthreads();
    }

    float hh[4], ss[4], dv[4];
#pragma unroll
    for (int n = 0; n < 4; ++n) {
        hh[n] = hist[nb + ni * 4 + n];
        ss[n] = subg[nb + ni * 4 + n];
        dv[n] = dinv[nb + ni * 4 + n];
    }
#pragma unroll
    for (int f = 0; f < 8; ++f) {
        float w256 = W[256 * 128 + fi * 8 + f];
        float w257 = W[257 * 128 + fi * 8 + f];
#pragma unroll
        for (int n = 0; n < 4; ++n) acc[n][f] += hh[n] * w256 + ss[n] * w257;
    }

#pragma unroll
    for (int n = 0; n < 4; ++n) {
        float4 pk;
        __half2* ph = (__half2*)&pk;
#pragma unroll
        for (int k = 0; k < 4; ++k) {
            __half2 h;
            h.x = __float2half_rn(acc[n][2 * k + 0] * dv[n]);
            h.y = __float2half_rn(acc[n][2 * k + 1] * dv[n]);
            ph[k] = h;
        }
        *(float4*)(g1 + (size_t)(nb + ni * 4 + n) * 64 + fi * 4) = pk;
    }
}

// ------- GEMM layer 2: [N,128]x[128,64] fp32, epilogue g = dinv*h -> fp16 ----

__global__ __launch_bounds__(256) void k_gemm2(const float* __restrict__ Xin,
                                               const float* __restrict__ W,
                                               const float* __restrict__ dinv,
                                               __half2* __restrict__ g2) {
    __shared__ float Xs[64][33];
    __shared__ float Ws[32][68];
    const int t = threadIdx.x;
    const int nb = blockIdx.x * 64;
    const int fi = t & 15;
    const int ni = t >> 4;
    const int lxn = t >> 2;
    const int lxk = (t & 3) * 8;
    const int lwk = t >> 3;
    const int lwf = (t & 7) * 8;

    float acc[4][4];
#pragma unroll
    for (int n = 0; n < 4; ++n)
#pragma unroll
        for (int f = 0; f < 4; ++f) acc[n][f] = 0.f;

    for (int kc = 0; kc < 128; kc += 32) {
        const float* xp = Xin + (size_t)(nb + lxn) * 128 + kc + lxk;
        float4 xa = *(const float4*)xp;
        float4 xb = *(const float4*)(xp + 4);
        Xs[lxn][lxk + 0] = xa.x;
        Xs[lxn][lxk + 1] = xa.y;
        Xs[lxn][lxk + 2] = xa.z;
        Xs[lxn][lxk + 3] = xa.w;
        Xs[lxn][lxk + 4] = xb.x;
        Xs[lxn][lxk + 5] = xb.y;
        Xs[lxn][lxk + 6] = xb.z;
        Xs[lxn][lxk + 7] = xb.w;

        const float* wp = W + (size_t)(kc + lwk) * 64 + lwf;
        float4* wsp = (float4*)&Ws[lwk][lwf];
        wsp[0] = *(const float4*)(wp + 0);
        wsp[1] = *(const float4*)(wp + 4);
        __syncthreads();

#pragma unroll
        for (int kk = 0; kk < 32; ++kk) {
            float4 wv = *(const float4*)&Ws[kk][fi * 4];
#pragma unroll
            for (int n = 0; n < 4; ++n) {
                float xv = Xs[ni * 4 + n][kk];
                acc[n][0] += xv * wv.x;
                acc[n][1] += xv * wv.y;
                acc[n][2] += xv * wv.z;
                acc[n][3] += xv * wv.w;
            }
        }
        __syncthreads();
    }

#pragma unroll
    for (int n = 0; n < 4; ++n) {
        float dv = dinv[nb + ni * 4 + n];
        float2 pk;
        __half2* ph = (__half2*)&pk;
#pragma unroll
        for (int k = 0; k < 2; ++k) {
            __half2 h;
            h.x = __float2half_rn(acc[n][2 * k + 0] * dv);
            h.y = __float2half_rn(acc[n][2 * k + 1] * dv);
            ph[k] = h;
        }
        *(float2*)(g2 + (size_t)(nb + ni * 4 + n) * 32 + fi * 2) = pk;
    }
}

// ------- GEMM layer 3: [N,64]x[64,8], epilogue g = dinv*h (fp32) -------------

__global__ __launch_bounds__(256) void k_gemm3(const float* __restrict__ Xin,
                                               const float* __restrict__ W,
                                               const float* __restrict__ dinv,
                                               float* __restrict__ g3) {
    __shared__ float Ws[512];
    int t = threadIdx.x;
    Ws[t] = W[t];
    Ws[t + 256] = W[t + 256];
    __syncthreads();
    int i = blockIdx.x * 256 + t;
    if (i >= N_NODES) return;
    const float4* xp = (const float4*)(Xin + (size_t)i * 64);
    float acc[8];
#pragma unroll
    for (int f = 0; f < 8; ++f) acc[f] = 0.f;
#pragma unroll
    for (int k4 = 0; k4 < 16; ++k4) {
        float4 xv = xp[k4];
        float xs[4] = {xv.x, xv.y, xv.z, xv.w};
#pragma unroll
        for (int q = 0; q < 4; ++q) {
            int k = k4 * 4 + q;
            float4 w0 = *(const float4*)&Ws[k * 8];
            float4 w1 = *(const float4*)&Ws[k * 8 + 4];
            acc[0] += xs[q] * w0.x;
            acc[1] += xs[q] * w0.y;
            acc[2] += xs[q] * w0.z;
            acc[3] += xs[q] * w0.w;
            acc[4] += xs[q] * w1.x;
            acc[5] += xs[q] * w1.y;
            acc[6] += xs[q] * w1.z;
            acc[7] += xs[q] * w1.w;
        }
    }
    float dv = dinv[i];
    float* op = g3 + (size_t)i * 8;
    *(float4*)op = make_float4(acc[0] * dv, acc[1] * dv, acc[2] * dv, acc[3] * dv);
    *(float4*)(op + 4) = make_float4(acc[4] * dv, acc[5] * dv, acc[6] * dv, acc[7] * dv);
}

// ------- aggregation (fp16 payload): out[i] = relu(dinv_i*(sum_j g_j + g_i)+b)
// TPN lanes per node, each lane owns one half2 (2 features). TPN == F/2.

template <int F, int TPN>
__global__ __launch_bounds__(256) void k_aggh(const __half2* __restrict__ g,
                                              const int* __restrict__ row,
                                              const int* __restrict__ col,
                                              const float* __restrict__ dinv,
                                              const float* __restrict__ bias,
                                              float* __restrict__ out) {
    constexpr int H2 = F / 2;
    static_assert(TPN == H2, "one half2 per lane");
    constexpr int NPB = 256 / TPN;
    const int t = threadIdx.x;
    const int node = blockIdx.x * NPB + t / TPN;
    const int lane = t % TPN;

    float ax = 0.f, ay = 0.f;
    const int s = row[node];
    const int e = row[node + 1];
    int idx = s;
    for (; idx + 8 <= e; idx += 8) {
        int j[8];
#pragma unroll
        for (int u = 0; u < 8; ++u) j[u] = col[idx + u];
        __half2 h[8];
#pragma unroll
        for (int u = 0; u < 8; ++u) h[u] = g[(size_t)j[u] * H2 + lane];
#pragma unroll
        for (int u = 0; u < 8; ++u) {
            float2 f = __half22float2(h[u]);
            ax += f.x;
            ay += f.y;
        }
    }
    for (; idx < e; ++idx) {
        float2 f = __half22float2(g[(size_t)col[idx] * H2 + lane]);
        ax += f.x;
        ay += f.y;
    }
    float2 fs = __half22float2(g[(size_t)node * H2 + lane]);  // self-loop
    const float di = dinv[node];
    float2 b = *(const float2*)(bias + lane * 2);
    float2 o;
    o.x = fmaxf(di * (ax + fs.x) + b.x, 0.f);
    o.y = fmaxf(di * (ay + fs.y) + b.y, 0.f);
    *(float2*)(out + (size_t)node * F + lane * 2) = o;
}

// ------- aggregation layer 3 (fp32, F=8, pre-scaled payload) -----------------

__global__ __launch_bounds__(256) void k_agg8(const float* __restrict__ g,
                                              const int* __restrict__ row,
                                              const int* __restrict__ col,
                                              const float* __restrict__ dinv,
                                              const float* __restrict__ bias,
                                              float* __restrict__ out) {
    const int t = threadIdx.x;
    const int node = blockIdx.x * 32 + t / 8;
    const int lane = t & 7;
    float acc = 0.f;
    const int s = row[node];
    const int e = row[node + 1];
    int idx = s;
    for (; idx + 8 <= e; idx += 8) {
        int j[8];
#pragma unroll
        for (int u = 0; u < 8; ++u) j[u] = col[idx + u];
        float v[8];
#pragma unroll
        for (int u = 0; u < 8; ++u) v[u] = g[(size_t)j[u] * 8 + lane];
#pragma unroll
        for (int u = 0; u < 8; ++u) acc += v[u];
    }
    for (; idx < e; ++idx) acc += g[(size_t)col[idx] * 8 + lane];
    acc += g[(size_t)node * 8 + lane];  // self-loop
    out[(size_t)node * 8 + lane] = fmaxf(dinv[node] * acc + bias[lane], 0.f);
}

// ---------------- final linear: [N,8]x[8,3] + bc -----------------------------

__global__ __launch_bounds__(256) void k_final(const float* __restrict__ h,
                                               const float* __restrict__ Wc,
                                               const float* __restrict__ bc,
                                               float* __restrict__ out) {
    int i = blockIdx.x * 256 + threadIdx.x;
    if (i >= N_NODES) return;
    const float4* xp = (const float4*)(h + (size_t)i * 8);
    float4 x0 = xp[0], x1 = xp[1];
    float xs[8] = {x0.x, x0.y, x0.z, x0.w, x1.x, x1.y, x1.z, x1.w};
    float o0 = bc[0], o1 = bc[1], o2 = bc[2];
#pragma unroll
    for (int k = 0; k < 8; ++k) {
        o0 += xs[k] * Wc[k * 3 + 0];
        o1 += xs[k] * Wc[k * 3 + 1];
        o2 += xs[k] * Wc[k * 3 + 2];
    }
    out[(size_t)i * 3 + 0] = o0;
    out[(size_t)i * 3 + 1] = o1;
    out[(size_t)i * 3 + 2] = o2;
}

// ---------------- launch -----------------------------------------------------

extern "C" void kernel_launch(void* const* d_in, const int* in_sizes, int n_in,
                              void* d_out, int out_size, void* d_ws, size_t ws_size,
                              hipStream_t stream) {
    const float* latent = (const float*)d_in[0];
    const float* hist = (const float*)d_in[1];
    const float* subg = (const float*)d_in[2];
    const int* eidx = (const int*)d_in[3];
    const float* W1 = (const float*)d_in[4];
    const float* b1 = (const float*)d_in[5];
    const float* W2 = (const float*)d_in[6];
    const float* b2 = (const float*)d_in[7];
    const float* W3 = (const float*)d_in[8];
    const float* b3 = (const float*)d_in[9];
    const float* Wc = (const float*)d_in[10];
    const float* bc = (const float*)d_in[11];
    float* outp = (float*)d_out;

    char* ws = (char*)d_ws;
    size_t off = 0;
    auto take = [&](size_t bytes) -> void* {
        void* p = ws + off;
        off += (bytes + 255) & ~(size_t)255;
        return p;
    };
    float* dinv = (float*)take((size_t)N_NODES * 4);
    int* row = (int*)take((size_t)(N_NODES + 1) * 4);
    int* col = (int*)take((size_t)N_EDGES * 4);
    u32* entries = (u32*)take((size_t)N_EDGES * 4);
    int* bcnt = (int*)take((size_t)NBUCK * 4);
    int* boff = (int*)take((size_t)(NBUCK + 1) * 4);
    int* bcur = (int*)take((size_t)NBUCK * 4);
    __half2* bufH = (__half2*)take((size_t)N_NODES * 128 * 2);  // fp16 g (layers 1-2)
    float* bufA = (float*)take((size_t)N_NODES * 128 * 4);      // h2 [N,128] then g3 [N,8]
    float* bufB = (float*)take((size_t)N_NODES * 64 * 4);       // h3 [N,64] then h4 [N,8]

    const int* srcp = eidx;            // edge_index[0]
    const int* dstp = eidx + N_EDGES;  // edge_index[1]

    const int scat_blocks = (N_EDGES + 8191) / 8192;  // 391

    hipMemsetAsync(bcnt, 0, (size_t)NBUCK * 4, stream);
    k_bhist<<<scat_blocks, 256, 0, stream>>>(dstp, bcnt);
    k_bscan<<<1, 256, 0, stream>>>(bcnt, boff, bcur, row);
    k_scatter<<<scat_blocks, 256, 0, stream>>>(srcp, dstp, bcur, entries);
    k_prep<<<NBUCK, 256, 0, stream>>>(entries, boff, row, dinv, col);

    k_gemm1<<<N_NODES / 64, 256, 0, stream>>>(latent, hist, subg, W1, dinv, bufH);
    k_aggh<128, 64><<<N_NODES / 4, 256, 0, stream>>>(bufH, row, col, dinv, b1, bufA);
    k_gemm2<<<N_NODES / 64, 256, 0, stream>>>(bufA, W2, dinv, bufH);
    k_aggh<64, 32><<<N_NODES / 8, 256, 0, stream>>>(bufH, row, col, dinv, b2, bufB);
    k_gemm3<<<(N_NODES + 255) / 256, 256, 0, stream>>>(bufB, W3, dinv, bufA);
    k_agg8<<<N_NODES / 32, 256, 0, stream>>>(bufA, row, col, dinv, b3, bufB);
    k_final<<<(N_NODES + 255) / 256, 256, 0, stream>>>(bufB, Wc, bc, outp);
}

// Round 6
// 868.406 us; speedup vs baseline: 1.8441x; 1.0422x over previous
//
#include <hip/hip_runtime.h>
#include <hip/hip_fp16.h>

// 3-layer GCN (fp32 compute): bucketed CSR build + (GEMM -> gather-aggregate) x3
// + final linear.
// Round 6: k_gemm1 rebuilt as 128x128 block tile, 8x8 per-thread micro-tile,
// feature split {fi*4, 64+fi*4} -> Ws LDS reads 2-way (free) instead of 4-way
// conflict (3.5e7 conflict cycles in r5); 64 FMA per 10 LDS ops -> VALU-bound.

#define N_NODES 200000
#define N_EDGES 3200000
#define NBUCK 782            // ceil(200000/256)

static_assert(N_NODES % 64 == 0, "tiling");
static_assert((NBUCK - 1) * 256 < N_NODES && NBUCK * 256 >= N_NODES, "buckets");

typedef unsigned int u32;

// ---------------- bucket histogram ----------------

__global__ __launch_bounds__(256) void k_bhist(const int* __restrict__ dst,
                                               int* __restrict__ bcnt) {
    __shared__ int lh[NBUCK];
    int t = threadIdx.x;
    for (int b = t; b < NBUCK; b += 256) lh[b] = 0;
    __syncthreads();
    long e0 = (long)blockIdx.x * 8192;
    for (int k = 0; k < 32; ++k) {
        long e = e0 + k * 256 + t;
        if (e < N_EDGES) atomicAdd(&lh[dst[e] >> 8], 1);
    }
    __syncthreads();
    for (int b = t; b < NBUCK; b += 256)
        if (lh[b]) atomicAdd(&bcnt[b], lh[b]);
}

// ---------------- bucket scan (1 block) ----------------

__global__ __launch_bounds__(256) void k_bscan(const int* __restrict__ bcnt,
                                               int* __restrict__ boff,
                                               int* __restrict__ bcur,
                                               int* __restrict__ row) {
    __shared__ int sm[256];
    int t = threadIdx.x;
    int base = t * 4;
    int a0 = (base + 0 < NBUCK) ? bcnt[base + 0] : 0;
    int a1 = (base + 1 < NBUCK) ? bcnt[base + 1] : 0;
    int a2 = (base + 2 < NBUCK) ? bcnt[base + 2] : 0;
    int a3 = (base + 3 < NBUCK) ? bcnt[base + 3] : 0;
    int s = a0 + a1 + a2 + a3;
    sm[t] = s;
    __syncthreads();
    for (int o = 1; o < 256; o <<= 1) {
        int v = (t >= o) ? sm[t - o] : 0;
        __syncthreads();
        sm[t] += v;
        __syncthreads();
    }
    int excl = sm[t] - s;
    if (base + 0 < NBUCK) { boff[base + 0] = excl;               bcur[base + 0] = excl; }
    if (base + 1 < NBUCK) { boff[base + 1] = excl + a0;          bcur[base + 1] = excl + a0; }
    if (base + 2 < NBUCK) { boff[base + 2] = excl + a0 + a1;     bcur[base + 2] = excl + a0 + a1; }
    if (base + 3 < NBUCK) { boff[base + 3] = excl + a0 + a1 + a2; bcur[base + 3] = excl + a0 + a1 + a2; }
    if (t == 255) { boff[NBUCK] = N_EDGES; row[N_NODES] = N_EDGES; }
}

// ------------- chunked scatter: entries[p] = (src<<8)|dst_local -------------

__global__ __launch_bounds__(256) void k_scatter(const int* __restrict__ src,
                                                 const int* __restrict__ dst,
                                                 int* __restrict__ bcur,
                                                 u32* __restrict__ entries) {
    __shared__ int lh[NBUCK];
    __shared__ int base[NBUCK];
    __shared__ int lcur[NBUCK];
    int t = threadIdx.x;
    for (int b = t; b < NBUCK; b += 256) lh[b] = 0;
    __syncthreads();
    long e0 = (long)blockIdx.x * 8192;
    for (int k = 0; k < 32; ++k) {
        long e = e0 + k * 256 + t;
        if (e < N_EDGES) atomicAdd(&lh[dst[e] >> 8], 1);
    }
    __syncthreads();
    for (int b = t; b < NBUCK; b += 256) {
        base[b] = atomicAdd(&bcur[b], lh[b]);
        lcur[b] = 0;
    }
    __syncthreads();
    for (int k = 0; k < 32; ++k) {
        long e = e0 + k * 256 + t;
        if (e < N_EDGES) {
            int d = dst[e];
            int bkt = d >> 8;
            int p = base[bkt] + atomicAdd(&lcur[bkt], 1);
            entries[p] = ((u32)src[e] << 8) | (u32)(d & 255);
        }
    }
}

// --- per-bucket prep: deg/row/dinv + col fill, all L2-local to one block ----

__global__ __launch_bounds__(256) void k_prep(const u32* __restrict__ entries,
                                              const int* __restrict__ boff,
                                              int* __restrict__ row,
                                              float* __restrict__ dinv,
                                              int* __restrict__ col) {
    __shared__ int lh[256];
    __shared__ int sc[256];
    __shared__ int cur[256];
    const int b = blockIdx.x, t = threadIdx.x;
    const int s = boff[b], e = boff[b + 1];
    const int cnt = e - s;
    lh[t] = 0;
    __syncthreads();
    for (int i = t; i < cnt; i += 256) atomicAdd(&lh[entries[s + i] & 255], 1);
    __syncthreads();
    int my = lh[t];
    sc[t] = my;
    __syncthreads();
    for (int o = 1; o < 256; o <<= 1) {
        int v = (t >= o) ? sc[t - o] : 0;
        __syncthreads();
        sc[t] += v;
        __syncthreads();
    }
    int excl = sc[t] - my;
    int node = b * 256 + t;
    if (node < N_NODES) {
        row[node] = s + excl;
        dinv[node] = rsqrtf((float)(my + 1));  // +1 self-loop
    }
    cur[t] = s + excl;
    __syncthreads();
    for (int i = t; i < cnt; i += 256) {
        u32 en = entries[s + i];
        int p = atomicAdd(&cur[en & 255], 1);
        col[p] = (int)(en >> 8);
    }
}

// ------- GEMM layer 1: [N,258]x[258,128] fp32, epilogue g = dinv*h -> fp16 ---
// 128-node x 128-feat block, 8x8 micro-tile. Thread owns feats {fi*4, 64+fi*4}
// (2-way LDS banks, free) and nodes ni*8..+7.

__global__ __launch_bounds__(256) void k_gemm1(const float* __restrict__ X,
                                               const float* __restrict__ hist,
                                               const float* __restrict__ subg,
                                               const float* __restrict__ W,
                                               const float* __restrict__ dinv,
                                               __half2* __restrict__ g1) {
    __shared__ float Xs[128][33];   // [node][k], +1 pad
    __shared__ float Ws[32][132];   // [k][f], +4 pad
    const int t = threadIdx.x;
    const int nb = blockIdx.x * 128;
    const int fi = t & 15;          // feats fi*4..+3 and 64+fi*4..+3
    const int ni = t >> 4;          // nodes ni*8..+7
    const int lxn = t >> 1;         // X loader: row 0..127
    const int lxk = (t & 1) * 16;   //            k-offset 0/16 (16 floats)
    const int lwk = t >> 3;         // W loader: k row 0..31
    const int lwf = (t & 7) * 16;   //            f-offset (16 floats)

    float acc[8][8];
#pragma unroll
    for (int n = 0; n < 8; ++n)
#pragma unroll
        for (int f = 0; f < 8; ++f) acc[n][f] = 0.f;

    int xrow = nb + lxn;
    if (xrow >= N_NODES) xrow = N_NODES - 1;  // clamp (junk, store guarded)

    for (int kc = 0; kc < 256; kc += 32) {
        const float* xp = X + (size_t)xrow * 256 + kc + lxk;
        float4* xsp = (float4*)&Xs[lxn][lxk];
        xsp[0] = *(const float4*)(xp + 0);
        xsp[1] = *(const float4*)(xp + 4);
        xsp[2] = *(const float4*)(xp + 8);
        xsp[3] = *(const float4*)(xp + 12);

        const float* wp = W + (size_t)(kc + lwk) * 128 + lwf;
        float4* wsp = (float4*)&Ws[lwk][lwf];
        wsp[0] = *(const float4*)(wp + 0);
        wsp[1] = *(const float4*)(wp + 4);
        wsp[2] = *(const float4*)(wp + 8);
        wsp[3] = *(const float4*)(wp + 12);
        __syncthreads();

#pragma unroll
        for (int kk = 0; kk < 32; ++kk) {
            float4 wa = *(const float4*)&Ws[kk][fi * 4];
            float4 wb = *(const float4*)&Ws[kk][64 + fi * 4];
#pragma unroll
            for (int n = 0; n < 8; ++n) {
                float xv = Xs[ni * 8 + n][kk];
                acc[n][0] += xv * wa.x;
                acc[n][1] += xv * wa.y;
                acc[n][2] += xv * wa.z;
                acc[n][3] += xv * wa.w;
                acc[n][4] += xv * wb.x;
                acc[n][5] += xv * wb.y;
                acc[n][6] += xv * wb.z;
                acc[n][7] += xv * wb.w;
            }
        }
        __syncthreads();
    }

    // K tail: rows 256 (history), 257 (is_subgoal); epilogue scale by dinv.
    float w256[8], w257[8];
#pragma unroll
    for (int f = 0; f < 4; ++f) {
        w256[f] = W[256 * 128 + fi * 4 + f];
        w257[f] = W[257 * 128 + fi * 4 + f];
        w256[4 + f] = W[256 * 128 + 64 + fi * 4 + f];
        w257[4 + f] = W[257 * 128 + 64 + fi * 4 + f];
    }
#pragma unroll
    for (int n = 0; n < 8; ++n) {
        int node = nb + ni * 8 + n;
        if (node >= N_NODES) break;
        float hh = hist[node];
        float ss = subg[node];
        float dv = dinv[node];
        float2 pa, pb;
        __half2* ha = (__half2*)&pa;
        __half2* hb = (__half2*)&pb;
#pragma unroll
        for (int k = 0; k < 2; ++k) {
            __half2 va, vb;
            va.x = __float2half_rn((acc[n][2 * k + 0] + hh * w256[2 * k + 0] + ss * w257[2 * k + 0]) * dv);
            va.y = __float2half_rn((acc[n][2 * k + 1] + hh * w256[2 * k + 1] + ss * w257[2 * k + 1]) * dv);
            vb.x = __float2half_rn((acc[n][4 + 2 * k + 0] + hh * w256[4 + 2 * k + 0] + ss * w257[4 + 2 * k + 0]) * dv);
            vb.y = __float2half_rn((acc[n][4 + 2 * k + 1] + hh * w256[4 + 2 * k + 1] + ss * w257[4 + 2 * k + 1]) * dv);
            ha[k] = va;
            hb[k] = vb;
        }
        *(float2*)(g1 + (size_t)node * 64 + fi * 2) = pa;
        *(float2*)(g1 + (size_t)node * 64 + 32 + fi * 2) = pb;
    }
}

// ------- GEMM layer 2: [N,128]x[128,64] fp32, epilogue g = dinv*h -> fp16 ----

__global__ __launch_bounds__(256) void k_gemm2(const float* __restrict__ Xin,
                                               const float* __restrict__ W,
                                               const float* __restrict__ dinv,
                                               __half2* __restrict__ g2) {
    __shared__ float Xs[64][33];
    __shared__ float Ws[32][68];
    const int t = threadIdx.x;
    const int nb = blockIdx.x * 64;
    const int fi = t & 15;
    const int ni = t >> 4;
    const int lxn = t >> 2;
    const int lxk = (t & 3) * 8;
    const int lwk = t >> 3;
    const int lwf = (t & 7) * 8;

    float acc[4][4];
#pragma unroll
    for (int n = 0; n < 4; ++n)
#pragma unroll
        for (int f = 0; f < 4; ++f) acc[n][f] = 0.f;

    for (int kc = 0; kc < 128; kc += 32) {
        const float* xp = Xin + (size_t)(nb + lxn) * 128 + kc + lxk;
        float4 xa = *(const float4*)xp;
        float4 xb = *(const float4*)(xp + 4);
        Xs[lxn][lxk + 0] = xa.x;
        Xs[lxn][lxk + 1] = xa.y;
        Xs[lxn][lxk + 2] = xa.z;
        Xs[lxn][lxk + 3] = xa.w;
        Xs[lxn][lxk + 4] = xb.x;
        Xs[lxn][lxk + 5] = xb.y;
        Xs[lxn][lxk + 6] = xb.z;
        Xs[lxn][lxk + 7] = xb.w;

        const float* wp = W + (size_t)(kc + lwk) * 64 + lwf;
        float4* wsp = (float4*)&Ws[lwk][lwf];
        wsp[0] = *(const float4*)(wp + 0);
        wsp[1] = *(const float4*)(wp + 4);
        __syncthreads();

#pragma unroll
        for (int kk = 0; kk < 32; ++kk) {
            float4 wv = *(const float4*)&Ws[kk][fi * 4];
#pragma unroll
            for (int n = 0; n < 4; ++n) {
                float xv = Xs[ni * 4 + n][kk];
                acc[n][0] += xv * wv.x;
                acc[n][1] += xv * wv.y;
                acc[n][2] += xv * wv.z;
                acc[n][3] += xv * wv.w;
            }
        }
        __syncthreads();
    }

#pragma unroll
    for (int n = 0; n < 4; ++n) {
        float dv = dinv[nb + ni * 4 + n];
        float2 pk;
        __half2* ph = (__half2*)&pk;
#pragma unroll
        for (int k = 0; k < 2; ++k) {
            __half2 h;
            h.x = __float2half_rn(acc[n][2 * k + 0] * dv);
            h.y = __float2half_rn(acc[n][2 * k + 1] * dv);
            ph[k] = h;
        }
        *(float2*)(g2 + (size_t)(nb + ni * 4 + n) * 32 + fi * 2) = pk;
    }
}

// ------- GEMM layer 3: [N,64]x[64,8], epilogue g = dinv*h (fp32) -------------

__global__ __launch_bounds__(256) void k_gemm3(const float* __restrict__ Xin,
                                               const float* __restrict__ W,
                                               const float* __restrict__ dinv,
                                               float* __restrict__ g3) {
    __shared__ float Ws[512];
    int t = threadIdx.x;
    Ws[t] = W[t];
    Ws[t + 256] = W[t + 256];
    __syncthreads();
    int i = blockIdx.x * 256 + t;
    if (i >= N_NODES) return;
    const float4* xp = (const float4*)(Xin + (size_t)i * 64);
    float acc[8];
#pragma unroll
    for (int f = 0; f < 8; ++f) acc[f] = 0.f;
#pragma unroll
    for (int k4 = 0; k4 < 16; ++k4) {
        float4 xv = xp[k4];
        float xs[4] = {xv.x, xv.y, xv.z, xv.w};
#pragma unroll
        for (int q = 0; q < 4; ++q) {
            int k = k4 * 4 + q;
            float4 w0 = *(const float4*)&Ws[k * 8];
            float4 w1 = *(const float4*)&Ws[k * 8 + 4];
            acc[0] += xs[q] * w0.x;
            acc[1] += xs[q] * w0.y;
            acc[2] += xs[q] * w0.z;
            acc[3] += xs[q] * w0.w;
            acc[4] += xs[q] * w1.x;
            acc[5] += xs[q] * w1.y;
            acc[6] += xs[q] * w1.z;
            acc[7] += xs[q] * w1.w;
        }
    }
    float dv = dinv[i];
    float* op = g3 + (size_t)i * 8;
    *(float4*)op = make_float4(acc[0] * dv, acc[1] * dv, acc[2] * dv, acc[3] * dv);
    *(float4*)(op + 4) = make_float4(acc[4] * dv, acc[5] * dv, acc[6] * dv, acc[7] * dv);
}

// ------- aggregation (fp16 payload): out[i] = relu(dinv_i*(sum_j g_j + g_i)+b)

template <int F, int TPN>
__global__ __launch_bounds__(256) void k_aggh(const __half2* __restrict__ g,
                                              const int* __restrict__ row,
                                              const int* __restrict__ col,
                                              const float* __restrict__ dinv,
                                              const float* __restrict__ bias,
                                              float* __restrict__ out) {
    constexpr int H2 = F / 2;
    static_assert(TPN == H2, "one half2 per lane");
    constexpr int NPB = 256 / TPN;
    const int t = threadIdx.x;
    const int node = blockIdx.x * NPB + t / TPN;
    const int lane = t % TPN;

    float ax = 0.f, ay = 0.f;
    const int s = row[node];
    const int e = row[node + 1];
    int idx = s;
    for (; idx + 8 <= e; idx += 8) {
        int j[8];
#pragma unroll
        for (int u = 0; u < 8; ++u) j[u] = col[idx + u];
        __half2 h[8];
#pragma unroll
        for (int u = 0; u < 8; ++u) h[u] = g[(size_t)j[u] * H2 + lane];
#pragma unroll
        for (int u = 0; u < 8; ++u) {
            float2 f = __half22float2(h[u]);
            ax += f.x;
            ay += f.y;
        }
    }
    for (; idx < e; ++idx) {
        float2 f = __half22float2(g[(size_t)col[idx] * H2 + lane]);
        ax += f.x;
        ay += f.y;
    }
    float2 fs = __half22float2(g[(size_t)node * H2 + lane]);  // self-loop
    const float di = dinv[node];
    float2 b = *(const float2*)(bias + lane * 2);
    float2 o;
    o.x = fmaxf(di * (ax + fs.x) + b.x, 0.f);
    o.y = fmaxf(di * (ay + fs.y) + b.y, 0.f);
    *(float2*)(out + (size_t)node * F + lane * 2) = o;
}

// ------- aggregation layer 3 (fp32, F=8, pre-scaled payload) -----------------

__global__ __launch_bounds__(256) void k_agg8(const float* __restrict__ g,
                                              const int* __restrict__ row,
                                              const int* __restrict__ col,
                                              const float* __restrict__ dinv,
                                              const float* __restrict__ bias,
                                              float* __restrict__ out) {
    const int t = threadIdx.x;
    const int node = blockIdx.x * 32 + t / 8;
    const int lane = t & 7;
    float acc = 0.f;
    const int s = row[node];
    const int e = row[node + 1];
    int idx = s;
    for (; idx + 8 <= e; idx += 8) {
        int j[8];
#pragma unroll
        for (int u = 0; u < 8; ++u) j[u] = col[idx + u];
        float v[8];
#pragma unroll
        for (int u = 0; u < 8; ++u) v[u] = g[(size_t)j[u] * 8 + lane];
#pragma unroll
        for (int u = 0; u < 8; ++u) acc += v[u];
    }
    for (; idx < e; ++idx) acc += g[(size_t)col[idx] * 8 + lane];
    acc += g[(size_t)node * 8 + lane];  // self-loop
    out[(size_t)node * 8 + lane] = fmaxf(dinv[node] * acc + bias[lane], 0.f);
}

// ---------------- final linear: [N,8]x[8,3] + bc -----------------------------

__global__ __launch_bounds__(256) void k_final(const float* __restrict__ h,
                                               const float* __restrict__ Wc,
                                               const float* __restrict__ bc,
                                               float* __restrict__ out) {
    int i = blockIdx.x * 256 + threadIdx.x;
    if (i >= N_NODES) return;
    const float4* xp = (const float4*)(h + (size_t)i * 8);
    float4 x0 = xp[0], x1 = xp[1];
    float xs[8] = {x0.x, x0.y, x0.z, x0.w, x1.x, x1.y, x1.z, x1.w};
    float o0 = bc[0], o1 = bc[1], o2 = bc[2];
#pragma unroll
    for (int k = 0; k < 8; ++k) {
        o0 += xs[k] * Wc[k * 3 + 0];
        o1 += xs[k] * Wc[k * 3 + 1];
        o2 += xs[k] * Wc[k * 3 + 2];
    }
    out[(size_t)i * 3 + 0] = o0;
    out[(size_t)i * 3 + 1] = o1;
    out[(size_t)i * 3 + 2] = o2;
}

// ---------------- launch -----------------------------------------------------

extern "C" void kernel_launch(void* const* d_in, const int* in_sizes, int n_in,
                              void* d_out, int out_size, void* d_ws, size_t ws_size,
                              hipStream_t stream) {
    const float* latent = (const float*)d_in[0];
    const float* hist = (const float*)d_in[1];
    const float* subg = (const float*)d_in[2];
    const int* eidx = (const int*)d_in[3];
    const float* W1 = (const float*)d_in[4];
    const float* b1 = (const float*)d_in[5];
    const float* W2 = (const float*)d_in[6];
    const float* b2 = (const float*)d_in[7];
    const float* W3 = (const float*)d_in[8];
    const float* b3 = (const float*)d_in[9];
    const float* Wc = (const float*)d_in[10];
    const float* bc = (const float*)d_in[11];
    float* outp = (float*)d_out;

    char* ws = (char*)d_ws;
    size_t off = 0;
    auto take = [&](size_t bytes) -> void* {
        void* p = ws + off;
        off += (bytes + 255) & ~(size_t)255;
        return p;
    };
    float* dinv = (float*)take((size_t)N_NODES * 4);
    int* row = (int*)take((size_t)(N_NODES + 1) * 4);
    int* col = (int*)take((size_t)N_EDGES * 4);
    u32* entries = (u32*)take((size_t)N_EDGES * 4);
    int* bcnt = (int*)take((size_t)NBUCK * 4);
    int* boff = (int*)take((size_t)(NBUCK + 1) * 4);
    int* bcur = (int*)take((size_t)NBUCK * 4);
    __half2* bufH = (__half2*)take((size_t)N_NODES * 128 * 2);  // fp16 g (layers 1-2)
    float* bufA = (float*)take((size_t)N_NODES * 128 * 4);      // h2 [N,128] then g3 [N,8]
    float* bufB = (float*)take((size_t)N_NODES * 64 * 4);       // h3 [N,64] then h4 [N,8]

    const int* srcp = eidx;            // edge_index[0]
    const int* dstp = eidx + N_EDGES;  // edge_index[1]

    const int scat_blocks = (N_EDGES + 8191) / 8192;  // 391

    hipMemsetAsync(bcnt, 0, (size_t)NBUCK * 4, stream);
    k_bhist<<<scat_blocks, 256, 0, stream>>>(dstp, bcnt);
    k_bscan<<<1, 256, 0, stream>>>(bcnt, boff, bcur, row);
    k_scatter<<<scat_blocks, 256, 0, stream>>>(srcp, dstp, bcur, entries);
    k_prep<<<NBUCK, 256, 0, stream>>>(entries, boff, row, dinv, col);

    k_gemm1<<<(N_NODES + 127) / 128, 256, 0, stream>>>(latent, hist, subg, W1, dinv, bufH);
    k_aggh<128, 64><<<N_NODES / 4, 256, 0, stream>>>(bufH, row, col, dinv, b1, bufA);
    k_gemm2<<<N_NODES / 64, 256, 0, stream>>>(bufA, W2, dinv, bufH);
    k_aggh<64, 32><<<N_NODES / 8, 256, 0, stream>>>(bufH, row, col, dinv, b2, bufB);
    k_gemm3<<<(N_NODES + 255) / 256, 256, 0, stream>>>(bufB, W3, dinv, bufA);
    k_agg8<<<N_NODES / 32, 256, 0, stream>>>(bufA, row, col, dinv, b3, bufB);
    k_final<<<(N_NODES + 255) / 256, 256, 0, stream>>>(bufB, Wc, bc, outp);
}